// Round 1
// baseline (10470.962 us; speedup 1.0000x reference)
//
#include <hip/hip_runtime.h>
#include <math.h>

// ---------------- problem dims (fixed by setup_inputs) ----------------
#define T_FRAMES 10
#define C_FEAT   64
#define IMG_H    480
#define IMG_W    640
#define P_PIX    (IMG_H*IMG_W)     // 307200
#define MAP_H    250
#define MAP_W    250
#define M_CELLS  (MAP_H*MAP_W)     // 62500
#define D_MEM    256
#define GATES    768
#define N_CLS    20

// ===================== scan-phase kernels =====================

__global__ __launch_bounds__(256) void k_frame_init(float* __restrict__ new_hmap,
                                                    const float* __restrict__ hmap,
                                                    int* __restrict__ winner,
                                                    int* __restrict__ count) {
    int i = blockIdx.x * 256 + threadIdx.x;
    if (i < M_CELLS) { new_hmap[i] = hmap[i]; winner[i] = -1; }
    if (i == 0) *count = 0;
}

__global__ __launch_bounds__(256) void k_scatter_max(const int* __restrict__ proj,
                                                     const int* __restrict__ mask,
                                                     const float* __restrict__ heights,
                                                     float* __restrict__ new_hmap) {
    int p = blockIdx.x * 256 + threadIdx.x;
    if (p >= P_PIX) return;
    if (mask[p]) return;                       // outlier -> -inf, never wins
    int idx = MAP_W * proj[2*p + 1] + proj[2*p];
    float mh = heights[p] + 1000.0f;
    // all values >= 0 -> int-reinterpret compare is order-preserving
    atomicMax((int*)(new_hmap + idx), __float_as_int(mh));
}

__global__ __launch_bounds__(256) void k_winner(const int* __restrict__ proj,
                                                const int* __restrict__ mask,
                                                const float* __restrict__ heights,
                                                const float* __restrict__ new_hmap,
                                                int* __restrict__ winner) {
    int p = blockIdx.x * 256 + threadIdx.x;
    if (p >= P_PIX) return;
    if (mask[p]) return;
    int idx = MAP_W * proj[2*p + 1] + proj[2*p];
    float mh = heights[p] + 1000.0f;
    if (mh == new_hmap[idx]) atomicMax(winner + idx, p);
}

__global__ __launch_bounds__(256) void k_compact(const float* __restrict__ new_hmap,
                                                 float* __restrict__ hmap,
                                                 float* __restrict__ observed,
                                                 int* __restrict__ updlist,
                                                 int* __restrict__ count) {
    int m = blockIdx.x * 256 + threadIdx.x;
    if (m >= M_CELLS) return;
    float nh = new_hmap[m];
    if (nh > hmap[m]) {
        int pos = atomicAdd(count, 1);
        updlist[pos] = m;
        observed[m] = 1.0f;
        hmap[m] = nh;
    }
}

// ===================== GRU GEMM kernel =====================
// Block: 256 threads, tile = 16 cells x all 768 gates, K chunked by 16 through LDS.
// Thread tid owns gate triplet (tid, tid+256, tid+512) for all 16 cells
// -> GRU epilogue fuses in-register; state write is coalesced over tid.

#define GKC    16
#define GCELLS 16

__device__ __forceinline__ void gru_chunk(int k0, float aval,
    const float* __restrict__ w_ih, const float* __restrict__ w_hh,
    float (&acc)[GCELLS][3],
    float (*Wt)[GATES + 1], float (*At)[20],
    int tid, int cs, int kks)
{
    // stage W tile: 768 gates x 16 k, transposed to [k][gate] (pad 769 -> conflict-free)
    #pragma unroll 8
    for (int j = 0; j < 48; ++j) {
        int e = tid + j * 256;
        int g = e >> 4, kk = e & 15;
        int k = k0 + kk;
        const float* wsrc = (k < 64) ? (w_ih + g * 64 + k)
                                     : (w_hh + g * 256 + (k - 64));
        Wt[kk][g] = *wsrc;
    }
    At[cs][kks] = aval;
    __syncthreads();

    #pragma unroll
    for (int kq = 0; kq < 4; ++kq) {
        float w0[4], w1[4], w2[4];
        #pragma unroll
        for (int kk = 0; kk < 4; ++kk) {
            w0[kk] = Wt[kq*4 + kk][tid];
            w1[kk] = Wt[kq*4 + kk][tid + 256];
            w2[kk] = Wt[kq*4 + kk][tid + 512];
        }
        #pragma unroll
        for (int c = 0; c < GCELLS; ++c) {
            float4 a = *(const float4*)(&At[c][kq*4]);   // broadcast read
            acc[c][0] = fmaf(a.x, w0[0], acc[c][0]);
            acc[c][0] = fmaf(a.y, w0[1], acc[c][0]);
            acc[c][0] = fmaf(a.z, w0[2], acc[c][0]);
            acc[c][0] = fmaf(a.w, w0[3], acc[c][0]);
            acc[c][1] = fmaf(a.x, w1[0], acc[c][1]);
            acc[c][1] = fmaf(a.y, w1[1], acc[c][1]);
            acc[c][1] = fmaf(a.z, w1[2], acc[c][1]);
            acc[c][1] = fmaf(a.w, w1[3], acc[c][1]);
            acc[c][2] = fmaf(a.x, w2[0], acc[c][2]);
            acc[c][2] = fmaf(a.y, w2[1], acc[c][2]);
            acc[c][2] = fmaf(a.z, w2[2], acc[c][2]);
            acc[c][2] = fmaf(a.w, w2[3], acc[c][2]);
        }
    }
    __syncthreads();
}

__global__ __launch_bounds__(256) void k_gru(
    const float* __restrict__ feat_t,            // features + t*C*P
    const float* __restrict__ w_ih, const float* __restrict__ w_hh,
    const float* __restrict__ b_ih, const float* __restrict__ b_hh,
    const int* __restrict__ updlist, const int* __restrict__ count,
    const int* __restrict__ winner, float* __restrict__ state)
{
    int n = *count;
    int base = blockIdx.x * GCELLS;
    if (base >= n) return;

    __shared__ alignas(16) float Wt[GKC][GATES + 1];  // 49.2 KB
    __shared__ alignas(16) float At[GCELLS][20];
    __shared__ int mc[GCELLS];
    __shared__ int pw[GCELLS];

    int tid = threadIdx.x;
    if (tid < GCELLS) {
        int i = base + tid; if (i > n - 1) i = n - 1;   // tail: duplicate last cell
        int m = updlist[i];
        mc[tid] = m;
        pw[tid] = winner[m];
    }
    __syncthreads();

    float ai[GCELLS][3], ah[GCELLS][3];
    #pragma unroll
    for (int c = 0; c < GCELLS; ++c) {
        ai[c][0] = ai[c][1] = ai[c][2] = 0.f;
        ah[c][0] = ah[c][1] = ah[c][2] = 0.f;
    }

    int cs = tid >> 4, kks = tid & 15;
    int mcs = mc[cs];
    int pws = pw[cs];

    // x part: K = 0..63 (feature gather at winner pixel)
    #pragma unroll 1
    for (int k0 = 0; k0 < 64; k0 += GKC) {
        float aval = feat_t[(size_t)(k0 + kks) * P_PIX + pws];
        gru_chunk(k0, aval, w_ih, w_hh, ai, Wt, At, tid, cs, kks);
    }
    // h part: K = 64..319 (state rows)
    #pragma unroll 1
    for (int k0 = 64; k0 < 320; k0 += GKC) {
        float aval = state[(size_t)mcs * D_MEM + (k0 - 64) + kks];
        gru_chunk(k0, aval, w_ih, w_hh, ah, Wt, At, tid, cs, kks);
    }

    // epilogue: gates (r,z,n) = rows (tid, tid+256, tid+512)
    int rem = n - base; if (rem > GCELLS) rem = GCELLS;
    float bi0 = b_ih[tid], bi1 = b_ih[tid + 256], bi2 = b_ih[tid + 512];
    float bh0 = b_hh[tid], bh1 = b_hh[tid + 256], bh2 = b_hh[tid + 512];
    #pragma unroll
    for (int c = 0; c < GCELLS; ++c) {
        if (c < rem) {
            int m = mc[c];
            float r = 1.f / (1.f + expf(-((ai[c][0] + bi0) + (ah[c][0] + bh0))));
            float z = 1.f / (1.f + expf(-((ai[c][1] + bi1) + (ah[c][1] + bh1))));
            float nn = tanhf((ai[c][2] + bi2) + r * (ah[c][2] + bh2));
            float h = state[(size_t)m * D_MEM + tid];
            state[(size_t)m * D_MEM + tid] = (1.f - z) * nn + z * h;
        }
    }
}

// ===================== transpose state[M][256] -> mem[256][M] =====================

__global__ __launch_bounds__(256) void k_transpose(const float* __restrict__ state,
                                                   float* __restrict__ mem) {
    __shared__ float tile[64][65];
    int m0 = blockIdx.x * 64, c0 = blockIdx.y * 64;
    int lx = threadIdx.x & 63, ly = threadIdx.x >> 6;   // ly 0..3
    #pragma unroll
    for (int j = 0; j < 64; j += 4) {
        int m = m0 + ly + j;
        tile[ly + j][lx] = (m < M_CELLS) ? state[(size_t)m * D_MEM + c0 + lx] : 0.f;
    }
    __syncthreads();
    int m = m0 + lx;
    if (m < M_CELLS) {
        #pragma unroll
        for (int j = 0; j < 64; j += 4)
            mem[(size_t)(c0 + ly + j) * M_CELLS + m] = tile[lx][ly + j];
    }
}

// ===================== direct conv (NCHW planes), fused input-BN+ReLU =====================
// block tile 64x32 px, thread microtile 4x2 px x OCB output channels.

template<int KS, int OCB, bool NORM>
__global__ __launch_bounds__(256) void k_conv(const float* __restrict__ in,
                                              const float* __restrict__ wt,
                                              float* __restrict__ out,
                                              const float* __restrict__ scale,
                                              const float* __restrict__ shift,
                                              int CIN) {
    constexpr int PAD = KS / 2;
    constexpr int TW = 64, TH = 32;
    constexpr int IW0 = TW + KS - 1;                 // used cols
    constexpr int IW  = (KS == 7) ? 76 : 68;         // padded LDS row stride (16B-aligned rows)
    constexpr int IH  = TH + KS - 1;
    __shared__ alignas(16) float tile[IH * IW];
    __shared__ float wl[OCB * KS * KS];

    int tid = threadIdx.x;
    int x0 = blockIdx.x * TW, y0 = blockIdx.y * TH;
    int oc0 = blockIdx.z * OCB;
    int tx = (tid & 15) * 4, ty = (tid >> 4) * 2;

    float acc[OCB][2][4];
    #pragma unroll
    for (int o = 0; o < OCB; ++o)
        #pragma unroll
        for (int dy = 0; dy < 2; ++dy)
            #pragma unroll
            for (int dx = 0; dx < 4; ++dx) acc[o][dy][dx] = 0.f;

    for (int ci = 0; ci < CIN; ++ci) {
        const float* ip = in + (size_t)ci * M_CELLS;
        float sc = 0.f, sh = 0.f;
        if constexpr (NORM) { sc = scale[ci]; sh = shift[ci]; }
        // stage zero-padded input tile
        for (int e = tid; e < IH * IW0; e += 256) {
            int r = e / IW0, c = e - r * IW0;
            int gy = y0 + r - PAD, gx = x0 + c - PAD;
            float v = 0.f;
            if (gy >= 0 && gy < MAP_H && gx >= 0 && gx < MAP_W) {
                v = ip[gy * MAP_W + gx];
                if constexpr (NORM) v = fmaxf(fmaf(v, sc, sh), 0.f);
            }
            tile[r * IW + c] = v;
        }
        // stage weights for this ci
        for (int e = tid; e < OCB * KS * KS; e += 256)
            wl[e] = wt[(size_t)(oc0 + e / (KS * KS)) * CIN * KS * KS
                       + (size_t)ci * KS * KS + (e % (KS * KS))];
        __syncthreads();

        #pragma unroll
        for (int ky = 0; ky < KS; ++ky) {
            float rv[2][KS + 3];
            #pragma unroll
            for (int dy = 0; dy < 2; ++dy)
                #pragma unroll
                for (int j = 0; j < KS + 3; ++j)
                    rv[dy][j] = tile[(ty + ky + dy) * IW + tx + j];
            #pragma unroll
            for (int kx = 0; kx < KS; ++kx)
                #pragma unroll
                for (int o = 0; o < OCB; ++o) {
                    float w = wl[o * KS * KS + ky * KS + kx];
                    #pragma unroll
                    for (int dy = 0; dy < 2; ++dy)
                        #pragma unroll
                        for (int dx = 0; dx < 4; ++dx)
                            acc[o][dy][dx] = fmaf(rv[dy][kx + dx], w, acc[o][dy][dx]);
                }
        }
        __syncthreads();
    }

    #pragma unroll
    for (int o = 0; o < OCB; ++o)
        #pragma unroll
        for (int dy = 0; dy < 2; ++dy) {
            int y = y0 + ty + dy;
            if (y < MAP_H) {
                #pragma unroll
                for (int dx = 0; dx < 4; ++dx) {
                    int x = x0 + tx + dx;
                    if (x < MAP_W)
                        out[(size_t)(oc0 + o) * M_CELLS + y * MAP_W + x] = acc[o][dy][dx];
                }
            }
        }
}

// ===================== BN stats (training-mode batch stats) =====================

__global__ __launch_bounds__(256) void k_bnstats(const float* __restrict__ x,
                                                 const float* __restrict__ g,
                                                 const float* __restrict__ b,
                                                 float* __restrict__ scale,
                                                 float* __restrict__ shift) {
    int c = blockIdx.x;
    const float* p = x + (size_t)c * M_CELLS;
    double s = 0.0, s2 = 0.0;
    for (int i = threadIdx.x; i < M_CELLS; i += 256) {
        float v = p[i];
        s += v; s2 += (double)v * v;
    }
    __shared__ double ls[256], ls2[256];
    int tid = threadIdx.x;
    ls[tid] = s; ls2[tid] = s2;
    __syncthreads();
    for (int off = 128; off > 0; off >>= 1) {
        if (tid < off) { ls[tid] += ls[tid + off]; ls2[tid] += ls2[tid + off]; }
        __syncthreads();
    }
    if (tid == 0) {
        double mu  = ls[0] / (double)M_CELLS;
        double var = ls2[0] / (double)M_CELLS - mu * mu;
        double rs  = 1.0 / sqrt(var + 1e-5);
        double gg  = (double)g[c];
        scale[c] = (float)(gg * rs);
        shift[c] = (float)((double)b[c] - mu * rs * gg);
    }
}

// ===================== conv5 (1x1) + bias, fused input-BN+ReLU =====================

__global__ __launch_bounds__(256) void k_conv5(const float* __restrict__ x4,
                                               const float* __restrict__ w,
                                               const float* __restrict__ bias,
                                               const float* __restrict__ scale,
                                               const float* __restrict__ shift,
                                               float* __restrict__ sem) {
    __shared__ float wl[N_CLS * 48];
    __shared__ float scl[48], shf[48], bl[N_CLS];
    int tid = threadIdx.x;
    for (int e = tid; e < N_CLS * 48; e += 256) wl[e] = w[e];
    if (tid < 48) { scl[tid] = scale[tid]; shf[tid] = shift[tid]; }
    if (tid < N_CLS) bl[tid] = bias[tid];
    __syncthreads();
    int p = blockIdx.x * 256 + tid;
    if (p >= M_CELLS) return;
    float inr[48];
    #pragma unroll
    for (int c = 0; c < 48; ++c)
        inr[c] = fmaxf(fmaf(x4[(size_t)c * M_CELLS + p], scl[c], shf[c]), 0.f);
    #pragma unroll
    for (int o = 0; o < N_CLS; ++o) {
        float a = bl[o];
        #pragma unroll
        for (int c = 0; c < 48; ++c) a = fmaf(inr[c], wl[o * 48 + c], a);
        sem[(size_t)o * M_CELLS + p] = a;
    }
}

__global__ __launch_bounds__(256) void k_copyout(const float* __restrict__ observed,
                                                 const float* __restrict__ hmap,
                                                 float* __restrict__ out) {
    int m = blockIdx.x * 256 + threadIdx.x;
    if (m < M_CELLS) {
        out[(size_t)N_CLS * M_CELLS + m] = observed[m];
        out[(size_t)N_CLS * M_CELLS + M_CELLS + m] = hmap[m];
    }
}

// ===================== host launcher =====================

extern "C" void kernel_launch(void* const* d_in, const int* in_sizes, int n_in,
                              void* d_out, int out_size, void* d_ws, size_t ws_size,
                              hipStream_t stream) {
    (void)in_sizes; (void)n_in; (void)out_size; (void)ws_size;

    const float* features = (const float*)d_in[0];
    const int*   proj     = (const int*)d_in[1];
    const int*   mask     = (const int*)d_in[2];   // bool -> int32 per harness convention
    const float* heights  = (const float*)d_in[3];
    const float* w_ih  = (const float*)d_in[6];
    const float* w_hh  = (const float*)d_in[7];
    const float* b_ih  = (const float*)d_in[8];
    const float* b_hh  = (const float*)d_in[9];
    const float* c1_w  = (const float*)d_in[10];
    const float* bn1_g = (const float*)d_in[11];
    const float* bn1_b = (const float*)d_in[12];
    const float* c2_w  = (const float*)d_in[13];
    const float* bn2_g = (const float*)d_in[14];
    const float* bn2_b = (const float*)d_in[15];
    const float* c3_w  = (const float*)d_in[16];
    const float* bn3_g = (const float*)d_in[17];
    const float* bn3_b = (const float*)d_in[18];
    const float* c4_w  = (const float*)d_in[19];
    const float* bn4_g = (const float*)d_in[20];
    const float* bn4_b = (const float*)d_in[21];
    const float* c5_w  = (const float*)d_in[22];
    const float* c5_b  = (const float*)d_in[23];

    // ---- workspace layout (~129.3 MB), with aggressive aliasing ----
    char* ws = (char*)d_ws;
    float* state = (float*)(ws);                    // [0,64M)    live: scan..transpose
    float* mem   = (float*)(ws + 64000000);         // [64M,128M) live: transpose..conv1
    float* x1    = (float*)(ws);                    // [0,32M)    live: conv1..conv2  (aliases dead state)
    float* x2    = (float*)(ws + 64000000);         // [64M,80M)  live: conv2..conv3  (aliases dead mem)
    float* x3    = (float*)(ws + 40000000);         // [40M,52M)  live: conv3..conv4
    float* x4    = (float*)(ws + 80000000);         // [80M,92M)  live: conv4..conv5
    float* hmap     = (float*)(ws + 128000000);
    float* new_hmap = hmap + M_CELLS;
    float* observed = new_hmap + M_CELLS;
    int*   winner   = (int*)(observed + M_CELLS);
    int*   updlist  = winner + M_CELLS;
    int*   count    = updlist + M_CELLS;
    float* scales   = (float*)(count + 64);
    float* shifts   = scales + 512;

    hipMemsetAsync(state, 0, (size_t)M_CELLS * D_MEM * sizeof(float), stream);
    hipMemsetAsync(hmap, 0, M_CELLS * sizeof(float), stream);
    hipMemsetAsync(observed, 0, M_CELLS * sizeof(float), stream);

    const int PB = (P_PIX + 255) / 256;        // 1200
    const int MB = (M_CELLS + 255) / 256;      // 245
    const int GB = (M_CELLS + GCELLS - 1) / GCELLS;  // 3907

    for (int t = 0; t < T_FRAMES; ++t) {
        const int*   proj_t = proj + (size_t)t * P_PIX * 2;
        const int*   mask_t = mask + (size_t)t * P_PIX;
        const float* h_t    = heights + (size_t)t * P_PIX;
        const float* f_t    = features + (size_t)t * C_FEAT * P_PIX;
        k_frame_init<<<MB, 256, 0, stream>>>(new_hmap, hmap, winner, count);
        k_scatter_max<<<PB, 256, 0, stream>>>(proj_t, mask_t, h_t, new_hmap);
        k_winner<<<PB, 256, 0, stream>>>(proj_t, mask_t, h_t, new_hmap, winner);
        k_compact<<<MB, 256, 0, stream>>>(new_hmap, hmap, observed, updlist, count);
        k_gru<<<GB, 256, 0, stream>>>(f_t, w_ih, w_hh, b_ih, b_hh,
                                      updlist, count, winner, state);
    }

    k_transpose<<<dim3((M_CELLS + 63) / 64, D_MEM / 64), 256, 0, stream>>>(state, mem);

    // conv1 7x7 256->128 (no input BN)
    k_conv<7, 8, false><<<dim3(4, 8, 16), 256, 0, stream>>>(mem, c1_w, x1, nullptr, nullptr, 256);
    k_bnstats<<<128, 256, 0, stream>>>(x1, bn1_g, bn1_b, scales + 0, shifts + 0);
    // conv2 3x3 128->64 (input = relu(bn1(x1)))
    k_conv<3, 4, true><<<dim3(4, 8, 16), 256, 0, stream>>>(x1, c2_w, x2, scales + 0, shifts + 0, 128);
    k_bnstats<<<64, 256, 0, stream>>>(x2, bn2_g, bn2_b, scales + 128, shifts + 128);
    // conv3 3x3 64->48
    k_conv<3, 4, true><<<dim3(4, 8, 12), 256, 0, stream>>>(x2, c3_w, x3, scales + 128, shifts + 128, 64);
    k_bnstats<<<48, 256, 0, stream>>>(x3, bn3_g, bn3_b, scales + 192, shifts + 192);
    // conv4 3x3 48->48
    k_conv<3, 4, true><<<dim3(4, 8, 12), 256, 0, stream>>>(x3, c4_w, x4, scales + 192, shifts + 192, 48);
    k_bnstats<<<48, 256, 0, stream>>>(x4, bn4_g, bn4_b, scales + 240, shifts + 240);
    // conv5 1x1 48->20 + bias -> sem (d_out[0 : 20*62500))
    k_conv5<<<MB, 256, 0, stream>>>(x4, c5_w, c5_b, scales + 240, shifts + 240, (float*)d_out);

    k_copyout<<<MB, 256, 0, stream>>>(observed, hmap, (float*)d_out);
}

// Round 2
// 7997.337 us; speedup vs baseline: 1.3093x; 1.3093x over previous
//
#include <hip/hip_runtime.h>
#include <math.h>

// ---------------- problem dims (fixed by setup_inputs) ----------------
#define T_FRAMES 10
#define C_FEAT   64
#define IMG_H    480
#define IMG_W    640
#define P_PIX    (IMG_H*IMG_W)     // 307200
#define MAP_H    250
#define MAP_W    250
#define M_CELLS  (MAP_H*MAP_W)     // 62500
#define D_MEM    256
#define GATES    768
#define N_CLS    20

// padded conv plane geometry: interior (250x250) lives at origin (3,3) for the
// 7x7 conv input and (5,5) for 3x3 conv inputs; both fit in 262 rows x 272 cols.
#define PW  272
#define PH  262
#define PP  (PH*PW)                // 71264 floats per plane

// ===================== scan-phase kernels =====================

__global__ __launch_bounds__(256) void k_frame_init(float* __restrict__ new_hmap,
                                                    const float* __restrict__ hmap,
                                                    int* __restrict__ winner,
                                                    int* __restrict__ count) {
    int i = blockIdx.x * 256 + threadIdx.x;
    if (i < M_CELLS) { new_hmap[i] = hmap[i]; winner[i] = -1; }
    if (i == 0) *count = 0;
}

__global__ __launch_bounds__(256) void k_scatter_max(const int2* __restrict__ proj,
                                                     const int* __restrict__ mask,
                                                     const float* __restrict__ heights,
                                                     float* __restrict__ new_hmap) {
    int p = blockIdx.x * 256 + threadIdx.x;
    if (p >= P_PIX) return;
    if (mask[p]) return;                       // outlier -> -inf, never wins
    int2 pr = proj[p];
    int idx = MAP_W * pr.y + pr.x;
    float mh = heights[p] + 1000.0f;
    // all values >= 0 -> int-reinterpret compare is order-preserving
    atomicMax((int*)(new_hmap + idx), __float_as_int(mh));
}

__global__ __launch_bounds__(256) void k_winner(const int2* __restrict__ proj,
                                                const int* __restrict__ mask,
                                                const float* __restrict__ heights,
                                                const float* __restrict__ new_hmap,
                                                int* __restrict__ winner) {
    int p = blockIdx.x * 256 + threadIdx.x;
    if (p >= P_PIX) return;
    if (mask[p]) return;
    int2 pr = proj[p];
    int idx = MAP_W * pr.y + pr.x;
    float mh = heights[p] + 1000.0f;
    if (mh == new_hmap[idx]) atomicMax(winner + idx, p);
}

__global__ __launch_bounds__(256) void k_compact(const float* __restrict__ new_hmap,
                                                 float* __restrict__ hmap,
                                                 float* __restrict__ observed,
                                                 int* __restrict__ updlist,
                                                 int* __restrict__ count) {
    int m = blockIdx.x * 256 + threadIdx.x;
    if (m >= M_CELLS) return;
    float nh = new_hmap[m];
    if (nh > hmap[m]) {
        int pos = atomicAdd(count, 1);
        updlist[pos] = m;
        observed[m] = 1.0f;
        hmap[m] = nh;
    }
}

// ===================== GRU GEMM kernel =====================
// Block: 256 threads, tile = 32 cells x all 768 gates, K chunked by 16 through LDS.
// Thread tid owns gate triplet (tid, tid+256, tid+512). r,z gate pre-activations
// only need (gi+gh) so they share an accumulator; n needs inn and hn separately.
// acc[c] = { r_sum, z_sum, inn, hn }.

#define GKC    16
#define GCELLS 32

template<bool HPART>
__device__ __forceinline__ void gru_chunk(int k0, float a0, float a1,
    const float* __restrict__ w_ih, const float* __restrict__ w_hh,
    float (&acc)[GCELLS][4],
    float (*Wt)[GATES + 1], float (*At)[GKC + 4],
    int tid, int cs, int kks)
{
    // stage W tile: 768 gates x 16 k, transposed to [k][gate] (pad 769 -> conflict-free)
    #pragma unroll 8
    for (int j = 0; j < 48; ++j) {
        int e = tid + j * 256;
        int g = e >> 4, kk = e & 15;
        int k = k0 + kk;
        const float* wsrc = (k < 64) ? (w_ih + g * 64 + k)
                                     : (w_hh + g * 256 + (k - 64));
        Wt[kk][g] = *wsrc;
    }
    At[cs][kks] = a0;
    At[cs + 16][kks] = a1;
    __syncthreads();

    #pragma unroll
    for (int kq = 0; kq < 4; ++kq) {
        float w0[4], w1[4], w2[4];
        #pragma unroll
        for (int kk = 0; kk < 4; ++kk) {
            w0[kk] = Wt[kq*4 + kk][tid];
            w1[kk] = Wt[kq*4 + kk][tid + 256];
            w2[kk] = Wt[kq*4 + kk][tid + 512];
        }
        #pragma unroll
        for (int c = 0; c < GCELLS; ++c) {
            float4 a = *(const float4*)(&At[c][kq*4]);   // broadcast read
            float r = acc[c][0], z = acc[c][1], nn = HPART ? acc[c][3] : acc[c][2];
            r = fmaf(a.x, w0[0], r); r = fmaf(a.y, w0[1], r);
            r = fmaf(a.z, w0[2], r); r = fmaf(a.w, w0[3], r);
            z = fmaf(a.x, w1[0], z); z = fmaf(a.y, w1[1], z);
            z = fmaf(a.z, w1[2], z); z = fmaf(a.w, w1[3], z);
            nn = fmaf(a.x, w2[0], nn); nn = fmaf(a.y, w2[1], nn);
            nn = fmaf(a.z, w2[2], nn); nn = fmaf(a.w, w2[3], nn);
            acc[c][0] = r; acc[c][1] = z;
            if (HPART) acc[c][3] = nn; else acc[c][2] = nn;
        }
    }
    __syncthreads();
}

__global__ __launch_bounds__(256) void k_gru(
    const float* __restrict__ feat_t,            // features + t*C*P
    const float* __restrict__ w_ih, const float* __restrict__ w_hh,
    const float* __restrict__ b_ih, const float* __restrict__ b_hh,
    const int* __restrict__ updlist, const int* __restrict__ count,
    const int* __restrict__ winner, float* __restrict__ state)
{
    int n = *count;
    int base = blockIdx.x * GCELLS;
    if (base >= n) return;

    __shared__ alignas(16) float Wt[GKC][GATES + 1];  // 49.2 KB
    __shared__ alignas(16) float At[GCELLS][GKC + 4];
    __shared__ int mc[GCELLS];
    __shared__ int pw[GCELLS];

    int tid = threadIdx.x;
    if (tid < GCELLS) {
        int i = base + tid; if (i > n - 1) i = n - 1;   // tail: duplicate last cell
        int m = updlist[i];
        mc[tid] = m;
        pw[tid] = winner[m];
    }
    __syncthreads();

    float acc[GCELLS][4];
    #pragma unroll
    for (int c = 0; c < GCELLS; ++c) {
        acc[c][0] = acc[c][1] = acc[c][2] = acc[c][3] = 0.f;
    }

    int cs = tid >> 4, kks = tid & 15;
    int m0 = mc[cs],      p0 = pw[cs];
    int m1 = mc[cs + 16], p1 = pw[cs + 16];

    // x part: K = 0..63 (feature gather at winner pixel)
    #pragma unroll 1
    for (int k0 = 0; k0 < 64; k0 += GKC) {
        float a0 = feat_t[(size_t)(k0 + kks) * P_PIX + p0];
        float a1 = feat_t[(size_t)(k0 + kks) * P_PIX + p1];
        gru_chunk<false>(k0, a0, a1, w_ih, w_hh, acc, Wt, At, tid, cs, kks);
    }
    // h part: K = 64..319 (state rows)
    #pragma unroll 1
    for (int k0 = 64; k0 < 320; k0 += GKC) {
        float a0 = state[(size_t)m0 * D_MEM + (k0 - 64) + kks];
        float a1 = state[(size_t)m1 * D_MEM + (k0 - 64) + kks];
        gru_chunk<true>(k0, a0, a1, w_ih, w_hh, acc, Wt, At, tid, cs, kks);
    }

    // epilogue
    int rem = n - base; if (rem > GCELLS) rem = GCELLS;
    float brz0 = b_ih[tid] + b_hh[tid];
    float brz1 = b_ih[tid + 256] + b_hh[tid + 256];
    float bi2  = b_ih[tid + 512];
    float bh2  = b_hh[tid + 512];
    #pragma unroll
    for (int c = 0; c < GCELLS; ++c) {
        if (c < rem) {
            int m = mc[c];
            float r = 1.f / (1.f + expf(-(acc[c][0] + brz0)));
            float z = 1.f / (1.f + expf(-(acc[c][1] + brz1)));
            float nn = tanhf((acc[c][2] + bi2) + r * (acc[c][3] + bh2));
            float h = state[(size_t)m * D_MEM + tid];
            state[(size_t)m * D_MEM + tid] = (1.f - z) * nn + z * h;
        }
    }
}

// ===================== transpose state[M][256] -> mem_pad[256][PH][PW] =====================
// interior origin (3,3) for the 7x7 conv.

__global__ __launch_bounds__(256) void k_transpose(const float* __restrict__ state,
                                                   float* __restrict__ mem_pad) {
    __shared__ float tile[64][65];
    int m0 = blockIdx.x * 64, c0 = blockIdx.y * 64;
    int lx = threadIdx.x & 63, ly = threadIdx.x >> 6;   // ly 0..3
    #pragma unroll
    for (int j = 0; j < 64; j += 4) {
        int m = m0 + ly + j;
        tile[ly + j][lx] = (m < M_CELLS) ? state[(size_t)m * D_MEM + c0 + lx] : 0.f;
    }
    __syncthreads();
    int m = m0 + lx;
    if (m < M_CELLS) {
        int y = m / MAP_W, x = m - y * MAP_W;
        size_t po = (size_t)(y + 3) * PW + (x + 3);
        #pragma unroll
        for (int j = 0; j < 64; j += 4)
            mem_pad[(size_t)(c0 + ly + j) * PP + po] = tile[lx][ly + j];
    }
}

// ===================== direct conv on padded planes =====================
// block tile 64x32 px, thread microtile 4x2 px x OCB output channels.
// in_base points at (interior_origin - PAD) of the padded input buffer, so all
// staging reads are unconditional, float4-aligned loads. Pads are pre-zeroed
// and inputs are pre-activated (k_bnapply), so no bounds checks anywhere.
// blockIdx.z = oc_chunk | (ci_chunk << OCSHIFT); ATOMIC builds accumulate
// ci-chunks via fp32 atomicAdd (exactly 2 commutative contributors).

template<int KS, int OCB, int OCSHIFT, bool OUTPAD, bool ATOMIC>
__global__ __launch_bounds__(256) void k_conv(const float* __restrict__ in_base,
                                              const float* __restrict__ wt,
                                              float* __restrict__ out_base,
                                              int CINC, int CIN_TOTAL) {
    constexpr int TW = 64, TH = 32;
    constexpr int RW  = TH + KS - 1;                 // staged rows
    constexpr int CW4 = (TW + KS - 1 + 3) / 4;       // staged float4s per row
    constexpr int IW  = CW4 * 4;                     // LDS row stride (multiple of 4)
    constexpr int RVW = (KS == 7) ? 12 : 8;
    __shared__ alignas(16) float tile[RW * IW];
    __shared__ alignas(16) float wl[KS * KS * OCB];  // transposed [k][oc]

    int tid = threadIdx.x;
    int x0 = blockIdx.x * TW, y0 = blockIdx.y * TH;
    int oc0 = (blockIdx.z & ((1 << OCSHIFT) - 1)) * OCB;
    int ci0 = (int)(blockIdx.z >> OCSHIFT) * CINC;
    int tx = (tid & 15) * 4, ty = (tid >> 4) * 2;

    float acc[OCB][2][4];
    #pragma unroll
    for (int o = 0; o < OCB; ++o)
        #pragma unroll
        for (int dy = 0; dy < 2; ++dy)
            #pragma unroll
            for (int dx = 0; dx < 4; ++dx) acc[o][dy][dx] = 0.f;

    for (int ci = 0; ci < CINC; ++ci) {
        const float* ip = in_base + (size_t)(ci0 + ci) * PP;
        // stage input tile: unconditional float4 copies
        #pragma unroll
        for (int e = tid; e < RW * CW4; e += 256) {
            int r = e / CW4, c = e - r * CW4;
            float4 v = *(const float4*)(ip + (size_t)(y0 + r) * PW + x0 + 4 * c);
            *(float4*)(&tile[r * IW + 4 * c]) = v;
        }
        // stage weights transposed [k][oc]
        for (int e = tid; e < KS * KS * OCB; e += 256) {
            int k = e / OCB, o = e - k * OCB;
            wl[e] = wt[(size_t)(oc0 + o) * CIN_TOTAL * KS * KS
                       + (size_t)(ci0 + ci) * KS * KS + k];
        }
        __syncthreads();

        #pragma unroll
        for (int ky = 0; ky < KS; ++ky) {
            float rv[2][RVW];
            #pragma unroll
            for (int dy = 0; dy < 2; ++dy) {
                const float4* tr = (const float4*)(&tile[(ty + ky + dy) * IW + tx]);
                #pragma unroll
                for (int q = 0; q < RVW / 4; ++q) {
                    float4 t = tr[q];
                    rv[dy][4*q+0] = t.x; rv[dy][4*q+1] = t.y;
                    rv[dy][4*q+2] = t.z; rv[dy][4*q+3] = t.w;
                }
            }
            #pragma unroll
            for (int kx = 0; kx < KS; ++kx) {
                float w[OCB];
                #pragma unroll
                for (int q = 0; q < OCB / 4; ++q) {
                    float4 t = *(const float4*)(&wl[(ky * KS + kx) * OCB + 4 * q]);
                    w[4*q+0] = t.x; w[4*q+1] = t.y; w[4*q+2] = t.z; w[4*q+3] = t.w;
                }
                #pragma unroll
                for (int o = 0; o < OCB; ++o)
                    #pragma unroll
                    for (int dy = 0; dy < 2; ++dy)
                        #pragma unroll
                        for (int dx = 0; dx < 4; ++dx)
                            acc[o][dy][dx] = fmaf(rv[dy][kx + dx], w[o], acc[o][dy][dx]);
            }
        }
        __syncthreads();
    }

    #pragma unroll
    for (int o = 0; o < OCB; ++o)
        #pragma unroll
        for (int dy = 0; dy < 2; ++dy) {
            int y = y0 + ty + dy;
            if (y < MAP_H) {
                #pragma unroll
                for (int dx = 0; dx < 4; ++dx) {
                    int x = x0 + tx + dx;
                    if (x < MAP_W) {
                        float* dst;
                        if constexpr (OUTPAD)
                            dst = out_base + (size_t)(oc0 + o) * PP + (size_t)y * PW + x;
                        else
                            dst = out_base + (size_t)(oc0 + o) * M_CELLS + y * MAP_W + x;
                        if constexpr (ATOMIC) atomicAdd(dst, acc[o][dy][dx]);
                        else                  *dst = acc[o][dy][dx];
                    }
                }
            }
        }
}

// ===================== BN stats (training-mode batch stats) =====================

__global__ __launch_bounds__(256) void k_bnstats(const float* __restrict__ base,
                                                 int rowstride, int planestride,
                                                 const float* __restrict__ g,
                                                 const float* __restrict__ b,
                                                 float* __restrict__ scale,
                                                 float* __restrict__ shift) {
    int c = blockIdx.x;
    const float* p = base + (size_t)c * planestride;
    double s = 0.0, s2 = 0.0;
    for (int i = threadIdx.x; i < M_CELLS; i += 256) {
        int y = i / MAP_W, x = i - y * MAP_W;
        float v = p[y * rowstride + x];
        s += v; s2 += (double)v * v;
    }
    __shared__ double ls[256], ls2[256];
    int tid = threadIdx.x;
    ls[tid] = s; ls2[tid] = s2;
    __syncthreads();
    for (int off = 128; off > 0; off >>= 1) {
        if (tid < off) { ls[tid] += ls[tid + off]; ls2[tid] += ls2[tid + off]; }
        __syncthreads();
    }
    if (tid == 0) {
        double mu  = ls[0] / (double)M_CELLS;
        double var = ls2[0] / (double)M_CELLS - mu * mu;
        double rs  = 1.0 / sqrt(var + 1e-5);
        double gg  = (double)g[c];
        scale[c] = (float)(gg * rs);
        shift[c] = (float)((double)b[c] - mu * rs * gg);
    }
}

// apply relu(bn(x)) in place on the interior of a padded plane (pads stay 0)

__global__ __launch_bounds__(256) void k_bnapply(float* __restrict__ base,
                                                 const float* __restrict__ scale,
                                                 const float* __restrict__ shift) {
    int c = blockIdx.x;
    float sc = scale[c], sh = shift[c];
    float* p = base + (size_t)c * PP;
    for (int i = threadIdx.x + blockIdx.y * 256; i < M_CELLS; i += 256 * gridDim.y) {
        int y = i / MAP_W, x = i - y * MAP_W;
        float v = p[y * PW + x];
        p[y * PW + x] = fmaxf(fmaf(v, sc, sh), 0.f);
    }
}

// ===================== conv5 (1x1) + bias, fused input-BN+ReLU =====================

__global__ __launch_bounds__(256) void k_conv5(const float* __restrict__ x4,
                                               const float* __restrict__ w,
                                               const float* __restrict__ bias,
                                               const float* __restrict__ scale,
                                               const float* __restrict__ shift,
                                               float* __restrict__ sem) {
    __shared__ float wl[N_CLS * 48];
    __shared__ float scl[48], shf[48], bl[N_CLS];
    int tid = threadIdx.x;
    for (int e = tid; e < N_CLS * 48; e += 256) wl[e] = w[e];
    if (tid < 48) { scl[tid] = scale[tid]; shf[tid] = shift[tid]; }
    if (tid < N_CLS) bl[tid] = bias[tid];
    __syncthreads();
    int p = blockIdx.x * 256 + tid;
    if (p >= M_CELLS) return;
    float inr[48];
    #pragma unroll
    for (int c = 0; c < 48; ++c)
        inr[c] = fmaxf(fmaf(x4[(size_t)c * M_CELLS + p], scl[c], shf[c]), 0.f);
    #pragma unroll
    for (int o = 0; o < N_CLS; ++o) {
        float a = bl[o];
        #pragma unroll
        for (int c = 0; c < 48; ++c) a = fmaf(inr[c], wl[o * 48 + c], a);
        sem[(size_t)o * M_CELLS + p] = a;
    }
}

__global__ __launch_bounds__(256) void k_copyout(const float* __restrict__ observed,
                                                 const float* __restrict__ hmap,
                                                 float* __restrict__ out) {
    int m = blockIdx.x * 256 + threadIdx.x;
    if (m < M_CELLS) {
        out[(size_t)N_CLS * M_CELLS + m] = observed[m];
        out[(size_t)N_CLS * M_CELLS + M_CELLS + m] = hmap[m];
    }
}

// ===================== host launcher =====================

extern "C" void kernel_launch(void* const* d_in, const int* in_sizes, int n_in,
                              void* d_out, int out_size, void* d_ws, size_t ws_size,
                              hipStream_t stream) {
    (void)in_sizes; (void)n_in; (void)out_size; (void)ws_size;

    const float* features = (const float*)d_in[0];
    const int*   proj     = (const int*)d_in[1];
    const int*   mask     = (const int*)d_in[2];
    const float* heights  = (const float*)d_in[3];
    const float* w_ih  = (const float*)d_in[6];
    const float* w_hh  = (const float*)d_in[7];
    const float* b_ih  = (const float*)d_in[8];
    const float* b_hh  = (const float*)d_in[9];
    const float* c1_w  = (const float*)d_in[10];
    const float* bn1_g = (const float*)d_in[11];
    const float* bn1_b = (const float*)d_in[12];
    const float* c2_w  = (const float*)d_in[13];
    const float* bn2_g = (const float*)d_in[14];
    const float* bn2_b = (const float*)d_in[15];
    const float* c3_w  = (const float*)d_in[16];
    const float* bn3_g = (const float*)d_in[17];
    const float* bn3_b = (const float*)d_in[18];
    const float* c4_w  = (const float*)d_in[19];
    const float* bn4_g = (const float*)d_in[20];
    const float* bn4_b = (const float*)d_in[21];
    const float* c5_w  = (const float*)d_in[22];
    const float* c5_b  = (const float*)d_in[23];

    // ---- workspace layout (~138.4 MB), with aggressive aliasing ----
    // region A [0, 64M): state (scan..transpose) -> x1_pad [0,36.5M) + x3_pad [40M,53.7M)
    // region B [64M, 137M): mem_pad (transpose..conv1) -> x2_pad [64M,82.3M) + x4 [90M,102M)
    char* ws = (char*)d_ws;
    float* state   = (float*)(ws);
    float* x1_pad  = (float*)(ws);
    float* x3_pad  = (float*)(ws + 40000000);
    float* mem_pad = (float*)(ws + 64000000);
    float* x2_pad  = (float*)(ws + 64000000);
    float* x4      = (float*)(ws + 90000000);
    float* hmap     = (float*)(ws + 137000000);
    float* new_hmap = hmap + M_CELLS;
    float* observed = new_hmap + M_CELLS;
    int*   winner   = (int*)(observed + M_CELLS);
    int*   updlist  = winner + M_CELLS;
    int*   count    = updlist + M_CELLS;
    float* scales   = (float*)(count + 64);
    float* shifts   = scales + 512;

    hipMemsetAsync(state, 0, (size_t)M_CELLS * D_MEM * sizeof(float), stream);
    hipMemsetAsync(hmap, 0, M_CELLS * sizeof(float), stream);
    hipMemsetAsync(observed, 0, M_CELLS * sizeof(float), stream);
    hipMemsetAsync(mem_pad, 0, (size_t)256 * PP * sizeof(float), stream);  // pads + interior

    const int PB = (P_PIX + 255) / 256;        // 1200
    const int MB = (M_CELLS + 255) / 256;      // 245
    const int GB = (M_CELLS + GCELLS - 1) / GCELLS;  // 1954

    for (int t = 0; t < T_FRAMES; ++t) {
        const int2*  proj_t = (const int2*)(proj + (size_t)t * P_PIX * 2);
        const int*   mask_t = mask + (size_t)t * P_PIX;
        const float* h_t    = heights + (size_t)t * P_PIX;
        const float* f_t    = features + (size_t)t * C_FEAT * P_PIX;
        k_frame_init<<<MB, 256, 0, stream>>>(new_hmap, hmap, winner, count);
        k_scatter_max<<<PB, 256, 0, stream>>>(proj_t, mask_t, h_t, new_hmap);
        k_winner<<<PB, 256, 0, stream>>>(proj_t, mask_t, h_t, new_hmap, winner);
        k_compact<<<MB, 256, 0, stream>>>(new_hmap, hmap, observed, updlist, count);
        k_gru<<<GB, 256, 0, stream>>>(f_t, w_ih, w_hh, b_ih, b_hh,
                                      updlist, count, winner, state);
    }

    k_transpose<<<dim3((M_CELLS + 63) / 64, D_MEM / 64), 256, 0, stream>>>(state, mem_pad);

    // state region is dead now; zero its new tenants (x1_pad, x3_pad)
    hipMemsetAsync(x1_pad, 0, (size_t)128 * PP * sizeof(float), stream);
    hipMemsetAsync(x3_pad, 0, (size_t)48 * PP * sizeof(float), stream);

    // conv1 7x7 256->128, ci-split x2, atomic accumulate into padded x1
    k_conv<7, 8, 4, true, true><<<dim3(4, 8, 32), 256, 0, stream>>>(
        mem_pad, c1_w, x1_pad + 5 * PW + 5, 128, 256);
    hipMemsetAsync(x2_pad, 0, (size_t)64 * PP * sizeof(float), stream);   // mem_pad dead
    k_bnstats<<<128, 256, 0, stream>>>(x1_pad + 5 * PW + 5, PW, PP, bn1_g, bn1_b,
                                       scales + 0, shifts + 0);
    k_bnapply<<<dim3(128, 8), 256, 0, stream>>>(x1_pad + 5 * PW + 5, scales + 0, shifts + 0);

    // conv2 3x3 128->64, ci-split x2
    k_conv<3, 8, 3, true, true><<<dim3(4, 8, 16), 256, 0, stream>>>(
        x1_pad + 4 * PW + 4, c2_w, x2_pad + 5 * PW + 5, 64, 128);
    k_bnstats<<<64, 256, 0, stream>>>(x2_pad + 5 * PW + 5, PW, PP, bn2_g, bn2_b,
                                      scales + 128, shifts + 128);
    k_bnapply<<<dim3(64, 8), 256, 0, stream>>>(x2_pad + 5 * PW + 5, scales + 128, shifts + 128);

    // conv3 3x3 64->48
    k_conv<3, 4, 4, true, false><<<dim3(4, 8, 12), 256, 0, stream>>>(
        x2_pad + 4 * PW + 4, c3_w, x3_pad + 5 * PW + 5, 64, 64);
    k_bnstats<<<48, 256, 0, stream>>>(x3_pad + 5 * PW + 5, PW, PP, bn3_g, bn3_b,
                                      scales + 192, shifts + 192);
    k_bnapply<<<dim3(48, 8), 256, 0, stream>>>(x3_pad + 5 * PW + 5, scales + 192, shifts + 192);

    // conv4 3x3 48->48 -> compact x4
    k_conv<3, 4, 4, false, false><<<dim3(4, 8, 12), 256, 0, stream>>>(
        x3_pad + 4 * PW + 4, c4_w, x4, 48, 48);
    k_bnstats<<<48, 256, 0, stream>>>(x4, MAP_W, M_CELLS, bn4_g, bn4_b,
                                      scales + 240, shifts + 240);

    // conv5 1x1 48->20 + bias (fused bn4+relu) -> sem
    k_conv5<<<MB, 256, 0, stream>>>(x4, c5_w, c5_b, scales + 240, shifts + 240, (float*)d_out);

    k_copyout<<<MB, 256, 0, stream>>>(observed, hmap, (float*)d_out);
}

// Round 3
// 5397.253 us; speedup vs baseline: 1.9401x; 1.4817x over previous
//
#include <hip/hip_runtime.h>
#include <math.h>

// ---------------- problem dims (fixed by setup_inputs) ----------------
#define T_FRAMES 10
#define C_FEAT   64
#define IMG_H    480
#define IMG_W    640
#define P_PIX    (IMG_H*IMG_W)     // 307200
#define MAP_H    250
#define MAP_W    250
#define M_CELLS  (MAP_H*MAP_W)     // 62500
#define D_MEM    256
#define GATES    768
#define N_CLS    20

// padded channels-last plane geometry: interior origin (3,3), rows 262, width 272
#define PW  272
#define PH  262
#define PP  (PH*PW)                // 71264 px per padded plane

typedef __attribute__((ext_vector_type(8))) short s16x8;   // 8 bf16 (4 VGPR)
typedef __attribute__((ext_vector_type(4))) float f32x4;   // MFMA acc

__device__ __forceinline__ unsigned short f2bf(float f) {
    unsigned int u = __float_as_uint(f);
    u += 0x7fffu + ((u >> 16) & 1u);      // RNE
    return (unsigned short)(u >> 16);
}
__device__ __forceinline__ float bf2f(unsigned short b) {
    return __uint_as_float(((unsigned int)b) << 16);
}

// ===================== scan-phase kernels =====================

__global__ __launch_bounds__(256) void k_frame_init(float* __restrict__ new_hmap,
                                                    const float* __restrict__ hmap,
                                                    int* __restrict__ winner,
                                                    int* __restrict__ count) {
    int i = blockIdx.x * 256 + threadIdx.x;
    if (i < M_CELLS) { new_hmap[i] = hmap[i]; winner[i] = -1; }
    if (i == 0) *count = 0;
}

__global__ __launch_bounds__(256) void k_scatter_max(const int2* __restrict__ proj,
                                                     const int* __restrict__ mask,
                                                     const float* __restrict__ heights,
                                                     float* __restrict__ new_hmap) {
    int p = blockIdx.x * 256 + threadIdx.x;
    if (p >= P_PIX) return;
    if (mask[p]) return;                       // outlier -> -inf, never wins
    int2 pr = proj[p];
    int idx = MAP_W * pr.y + pr.x;
    float mh = heights[p] + 1000.0f;
    atomicMax((int*)(new_hmap + idx), __float_as_int(mh));  // all values >= 0
}

__global__ __launch_bounds__(256) void k_winner(const int2* __restrict__ proj,
                                                const int* __restrict__ mask,
                                                const float* __restrict__ heights,
                                                const float* __restrict__ new_hmap,
                                                int* __restrict__ winner) {
    int p = blockIdx.x * 256 + threadIdx.x;
    if (p >= P_PIX) return;
    if (mask[p]) return;
    int2 pr = proj[p];
    int idx = MAP_W * pr.y + pr.x;
    float mh = heights[p] + 1000.0f;
    if (mh == new_hmap[idx]) atomicMax(winner + idx, p);
}

__global__ __launch_bounds__(256) void k_compact(const float* __restrict__ new_hmap,
                                                 float* __restrict__ hmap,
                                                 float* __restrict__ observed,
                                                 int* __restrict__ updlist,
                                                 int* __restrict__ count) {
    int m = blockIdx.x * 256 + threadIdx.x;
    if (m >= M_CELLS) return;
    float nh = new_hmap[m];
    if (nh > hmap[m]) {
        int pos = atomicAdd(count, 1);
        updlist[pos] = m;
        observed[m] = 1.0f;
        hmap[m] = nh;
    }
}

// ===================== GRU GEMM kernel (unchanged, validated) =====================

#define GKC    16
#define GCELLS 32

template<bool HPART>
__device__ __forceinline__ void gru_chunk(int k0, float a0, float a1,
    const float* __restrict__ w_ih, const float* __restrict__ w_hh,
    float (&acc)[GCELLS][4],
    float (*Wt)[GATES + 1], float (*At)[GKC + 4],
    int tid, int cs, int kks)
{
    #pragma unroll 8
    for (int j = 0; j < 48; ++j) {
        int e = tid + j * 256;
        int g = e >> 4, kk = e & 15;
        int k = k0 + kk;
        const float* wsrc = (k < 64) ? (w_ih + g * 64 + k)
                                     : (w_hh + g * 256 + (k - 64));
        Wt[kk][g] = *wsrc;
    }
    At[cs][kks] = a0;
    At[cs + 16][kks] = a1;
    __syncthreads();

    #pragma unroll
    for (int kq = 0; kq < 4; ++kq) {
        float w0[4], w1[4], w2[4];
        #pragma unroll
        for (int kk = 0; kk < 4; ++kk) {
            w0[kk] = Wt[kq*4 + kk][tid];
            w1[kk] = Wt[kq*4 + kk][tid + 256];
            w2[kk] = Wt[kq*4 + kk][tid + 512];
        }
        #pragma unroll
        for (int c = 0; c < GCELLS; ++c) {
            float4 a = *(const float4*)(&At[c][kq*4]);
            float r = acc[c][0], z = acc[c][1], nn = HPART ? acc[c][3] : acc[c][2];
            r = fmaf(a.x, w0[0], r); r = fmaf(a.y, w0[1], r);
            r = fmaf(a.z, w0[2], r); r = fmaf(a.w, w0[3], r);
            z = fmaf(a.x, w1[0], z); z = fmaf(a.y, w1[1], z);
            z = fmaf(a.z, w1[2], z); z = fmaf(a.w, w1[3], z);
            nn = fmaf(a.x, w2[0], nn); nn = fmaf(a.y, w2[1], nn);
            nn = fmaf(a.z, w2[2], nn); nn = fmaf(a.w, w2[3], nn);
            acc[c][0] = r; acc[c][1] = z;
            if (HPART) acc[c][3] = nn; else acc[c][2] = nn;
        }
    }
    __syncthreads();
}

__global__ __launch_bounds__(256) void k_gru(
    const float* __restrict__ feat_t,
    const float* __restrict__ w_ih, const float* __restrict__ w_hh,
    const float* __restrict__ b_ih, const float* __restrict__ b_hh,
    const int* __restrict__ updlist, const int* __restrict__ count,
    const int* __restrict__ winner, float* __restrict__ state)
{
    int n = *count;
    int base = blockIdx.x * GCELLS;
    if (base >= n) return;

    __shared__ alignas(16) float Wt[GKC][GATES + 1];
    __shared__ alignas(16) float At[GCELLS][GKC + 4];
    __shared__ int mc[GCELLS];
    __shared__ int pw[GCELLS];

    int tid = threadIdx.x;
    if (tid < GCELLS) {
        int i = base + tid; if (i > n - 1) i = n - 1;
        int m = updlist[i];
        mc[tid] = m;
        pw[tid] = winner[m];
    }
    __syncthreads();

    float acc[GCELLS][4];
    #pragma unroll
    for (int c = 0; c < GCELLS; ++c)
        acc[c][0] = acc[c][1] = acc[c][2] = acc[c][3] = 0.f;

    int cs = tid >> 4, kks = tid & 15;
    int m0 = mc[cs],      p0 = pw[cs];
    int m1 = mc[cs + 16], p1 = pw[cs + 16];

    #pragma unroll 1
    for (int k0 = 0; k0 < 64; k0 += GKC) {
        float a0 = feat_t[(size_t)(k0 + kks) * P_PIX + p0];
        float a1 = feat_t[(size_t)(k0 + kks) * P_PIX + p1];
        gru_chunk<false>(k0, a0, a1, w_ih, w_hh, acc, Wt, At, tid, cs, kks);
    }
    #pragma unroll 1
    for (int k0 = 64; k0 < 320; k0 += GKC) {
        float a0 = state[(size_t)m0 * D_MEM + (k0 - 64) + kks];
        float a1 = state[(size_t)m1 * D_MEM + (k0 - 64) + kks];
        gru_chunk<true>(k0, a0, a1, w_ih, w_hh, acc, Wt, At, tid, cs, kks);
    }

    int rem = n - base; if (rem > GCELLS) rem = GCELLS;
    float brz0 = b_ih[tid] + b_hh[tid];
    float brz1 = b_ih[tid + 256] + b_hh[tid + 256];
    float bi2  = b_ih[tid + 512];
    float bh2  = b_hh[tid + 512];
    #pragma unroll
    for (int c = 0; c < GCELLS; ++c) {
        if (c < rem) {
            int m = mc[c];
            float r = 1.f / (1.f + expf(-(acc[c][0] + brz0)));
            float z = 1.f / (1.f + expf(-(acc[c][1] + brz1)));
            float nn = tanhf((acc[c][2] + bi2) + r * (acc[c][3] + bh2));
            float h = state[(size_t)m * D_MEM + tid];
            state[(size_t)m * D_MEM + tid] = (1.f - z) * nn + z * h;
        }
    }
}

// ===================== state -> padded channels-last bf16 =====================

__global__ __launch_bounds__(256) void k_cvt1(const float* __restrict__ state,
                                              short* __restrict__ in1) {
    int idx = blockIdx.x * 256 + threadIdx.x;       // (m, c8)
    if (idx >= M_CELLS * 32) return;
    int m = idx >> 5, c8 = (idx & 31) * 8;
    int y = m / MAP_W, x = m - y * MAP_W;
    const float* sp = state + (size_t)m * D_MEM + c8;
    unsigned int pk[4];
    #pragma unroll
    for (int q = 0; q < 4; ++q) {
        unsigned int lo = f2bf(sp[2*q]), hi = f2bf(sp[2*q+1]);
        pk[q] = lo | (hi << 16);
    }
    uint4 v = make_uint4(pk[0], pk[1], pk[2], pk[3]);
    *(uint4*)(in1 + ((size_t)(y + 3) * PW + (x + 3)) * 256 + c8) = v;
}

// ===================== weight pre-transform: [OC][CIN][KS][KS] f32 -> [tap][ci8][OCP][8] bf16 =====

__global__ __launch_bounds__(256) void k_wprep(const float* __restrict__ w,
                                               short* __restrict__ wm,
                                               int OC, int CIN, int OCP, int CINP, int KS) {
    int total = KS * KS * (CINP / 8) * OCP;
    int idx = blockIdx.x * 256 + threadIdx.x;
    if (idx >= total) return;
    int oc  = idx % OCP;
    int t2  = idx / OCP;
    int ci8 = t2 % (CINP / 8);
    int tap = t2 / (CINP / 8);
    unsigned int pk[4];
    #pragma unroll
    for (int q = 0; q < 4; ++q) {
        unsigned int h[2];
        #pragma unroll
        for (int e = 0; e < 2; ++e) {
            int ci = ci8 * 8 + 2*q + e;
            float v = (oc < OC && ci < CIN)
                ? w[((size_t)oc * CIN + ci) * KS * KS + tap] : 0.f;
            h[e] = f2bf(v);
        }
        pk[q] = h[0] | (h[1] << 16);
    }
    *(uint4*)(wm + (size_t)idx * 8) = make_uint4(pk[0], pk[1], pk[2], pk[3]);
}

// ===================== MFMA implicit-GEMM conv =====================
// Block: 256 thr = 4 waves; out tile 16x16 px x 64 oc. K = CINP channels x KS*KS taps.
// Input: padded channels-last bf16 [PH][PW][CINP], interior origin (3,3), pads zero,
// already BN+ReLU'd. Weights: wm[tap][ci8][OCT][8] (A-frag order, read from global/L1).
// Input patch (32 ci x (16+KS-1)^2 px) staged in XOR-swizzled LDS per ci-chunk.
// MFMA 16x16x32: A row=lane&15 (oc), B col=lane&15 (px), k=8*(lane>>4)+j;
// D col=lane&15, row=4*(lane>>4)+reg  [m89-verified C/D layout].

template<int CINP, int KS, bool F32OUT>
__global__ __launch_bounds__(256) void k_cmfma(const short* __restrict__ in,
                                               const short* __restrict__ wm,
                                               int OCT,
                                               void* __restrict__ out,
                                               int OCS) {
    constexpr int PAD = KS / 2;
    constexpr int PTW = 16 + KS - 1;
    __shared__ alignas(16) char patch[PTW * PTW * 64];

    const int tid = threadIdx.x;
    const int w   = tid >> 6;
    const int l   = tid & 63;
    const int u   = l & 15;
    const int s   = l >> 4;

    const int x0  = 3 + 16 * blockIdx.x;
    const int y0  = 3 + 16 * blockIdx.y;
    const int oc0 = 64 * blockIdx.z;

    f32x4 acc[4][4];   // [yy][o]
    #pragma unroll
    for (int yy = 0; yy < 4; ++yy)
        #pragma unroll
        for (int o = 0; o < 4; ++o)
            acc[yy][o] = (f32x4){0.f, 0.f, 0.f, 0.f};

    for (int ci0 = 0; ci0 < CINP; ci0 += 32) {
        __syncthreads();
        // stage patch: PTW*PTW px x 32 ci, 16B (8 ci) per thread-chunk
        for (int e = tid; e < PTW * PTW * 4; e += 256) {
            int c8 = e & 3;
            int pp = e >> 2;
            int px = pp % PTW, py = pp / PTW;
            int gy = y0 - PAD + py, gx = x0 - PAD + px;
            const short* g = in + ((size_t)gy * PW + gx) * CINP + ci0 + c8 * 8;
            int lb = (((py * PTW + px) * 64) + c8 * 16) ^ ((px & 3) << 4);
            *(uint4*)(patch + lb) = *(const uint4*)g;
        }
        __syncthreads();

        const short* wb = wm + ((size_t)(ci0 / 8 + s) * OCT + oc0 + u) * 8;

        for (int ky = 0; ky < KS; ++ky) {
            for (int kx = 0; kx < KS; ++kx) {
                const int tap = ky * KS + kx;
                const short* wt = wb + (size_t)tap * (CINP / 8) * OCT * 8;
                s16x8 a[4];
                #pragma unroll
                for (int o = 0; o < 4; ++o)
                    a[o] = *(const s16x8*)(wt + o * 16 * 8);
                const int px = kx + u;
                const int lb0 = ((px * 64) + s * 16) ^ ((px & 3) << 4);
                #pragma unroll
                for (int yy = 0; yy < 4; ++yy) {
                    int py = 4 * w + yy + ky;
                    s16x8 b = *(const s16x8*)(patch + py * PTW * 64 + lb0);
                    #pragma unroll
                    for (int o = 0; o < 4; ++o)
                        acc[yy][o] = __builtin_amdgcn_mfma_f32_16x16x32_bf16(
                            a[o], b, acc[yy][o], 0, 0, 0);
                }
            }
        }
    }

    // epilogue
    const int gx = x0 + u;
    if (gx >= 253) return;
    #pragma unroll
    for (int yy = 0; yy < 4; ++yy) {
        int gy = y0 + 4 * w + yy;
        if (gy >= 253) continue;
        #pragma unroll
        for (int o = 0; o < 4; ++o) {
            int oc = oc0 + o * 16 + s * 4;
            if constexpr (F32OUT) {
                int m = (gy - 3) * MAP_W + (gx - 3);
                float* op = (float*)out + (size_t)m * 48 + oc;
                #pragma unroll
                for (int r = 0; r < 4; ++r)
                    if (oc + r < 48) op[r] = acc[yy][o][r];
            } else {
                short* op = (short*)out + ((size_t)gy * PW + gx) * OCS + oc;
                unsigned int w0 = f2bf(acc[yy][o][0]) | ((unsigned int)f2bf(acc[yy][o][1]) << 16);
                unsigned int w1 = f2bf(acc[yy][o][2]) | ((unsigned int)f2bf(acc[yy][o][3]) << 16);
                *(uint2*)op = make_uint2(w0, w1);
            }
        }
    }
}

// ===================== BN stats / finalize / apply (channels-last) =====================

template<int CINP>
__global__ __launch_bounds__(256) void k_bnstats_cl(const short* __restrict__ in, // at (3,3)
                                                    float* __restrict__ sums,
                                                    float* __restrict__ sums2) {
    constexpr int QW = 256 / CINP;
    int c = threadIdx.x & (CINP - 1);
    int q = threadIdx.x / CINP;
    float s = 0.f, s2 = 0.f;
    int yb = blockIdx.x * 5;
    for (int y = yb; y < yb + 5; ++y)
        for (int x = q; x < MAP_W; x += QW) {
            float v = bf2f((unsigned short)in[((size_t)y * PW + x) * CINP + c]);
            s += v; s2 += v * v;
        }
    __shared__ float ls[256], ls2[256];
    ls[threadIdx.x] = s; ls2[threadIdx.x] = s2;
    __syncthreads();
    if (q == 0) {
        #pragma unroll
        for (int k = 1; k < QW; ++k) { s += ls[k * CINP + c]; s2 += ls2[k * CINP + c]; }
        atomicAdd(sums + c, s); atomicAdd(sums2 + c, s2);
    }
}

__global__ __launch_bounds__(256) void k_bnfinal(const float* __restrict__ sums,
                                                 const float* __restrict__ sums2,
                                                 const float* __restrict__ g,
                                                 const float* __restrict__ b,
                                                 int OC, int C,
                                                 float* __restrict__ scale,
                                                 float* __restrict__ shift) {
    int c = threadIdx.x;
    if (c >= C) return;
    if (c < OC) {
        float mu  = sums[c] * (1.f / M_CELLS);
        float var = sums2[c] * (1.f / M_CELLS) - mu * mu;
        float rs  = rsqrtf(var + 1e-5f);
        scale[c] = g[c] * rs;
        shift[c] = b[c] - mu * rs * g[c];
    } else { scale[c] = 0.f; shift[c] = 0.f; }
}

template<int CINP>
__global__ __launch_bounds__(256) void k_bnapply_cl(short* __restrict__ base, // at (3,3)
                                                    const float* __restrict__ scale,
                                                    const float* __restrict__ shift) {
    constexpr int NC8 = CINP / 8;
    int idx = blockIdx.x * 256 + threadIdx.x;
    if (idx >= M_CELLS * NC8) return;
    int p = idx / NC8, c8 = (idx % NC8) * 8;
    int y = p / MAP_W, x = p - y * MAP_W;
    short* ptr = base + ((size_t)y * PW + x) * CINP + c8;
    uint4 v = *(uint4*)ptr;
    unsigned int uu[4] = {v.x, v.y, v.z, v.w};
    unsigned int ro[4];
    #pragma unroll
    for (int q = 0; q < 4; ++q) {
        float f0 = bf2f((unsigned short)(uu[q] & 0xffffu));
        float f1 = bf2f((unsigned short)(uu[q] >> 16));
        f0 = fmaxf(fmaf(f0, scale[c8 + 2*q],     shift[c8 + 2*q]),     0.f);
        f1 = fmaxf(fmaf(f1, scale[c8 + 2*q + 1], shift[c8 + 2*q + 1]), 0.f);
        ro[q] = (unsigned int)f2bf(f0) | ((unsigned int)f2bf(f1) << 16);
    }
    *(uint4*)ptr = make_uint4(ro[0], ro[1], ro[2], ro[3]);
}

// BN stats for compact f32 channels-last [M][stride] (deterministic per-channel)
__global__ __launch_bounds__(256) void k_bnstats_s(const float* __restrict__ x,
                                                   int stride,
                                                   const float* __restrict__ g,
                                                   const float* __restrict__ b,
                                                   float* __restrict__ scale,
                                                   float* __restrict__ shift) {
    int c = blockIdx.x;
    const float* p = x + c;
    double s = 0.0, s2 = 0.0;
    for (int i = threadIdx.x; i < M_CELLS; i += 256) {
        float v = p[(size_t)i * stride];
        s += v; s2 += (double)v * v;
    }
    __shared__ double ls[256], ls2[256];
    int tid = threadIdx.x;
    ls[tid] = s; ls2[tid] = s2;
    __syncthreads();
    for (int off = 128; off > 0; off >>= 1) {
        if (tid < off) { ls[tid] += ls[tid + off]; ls2[tid] += ls2[tid + off]; }
        __syncthreads();
    }
    if (tid == 0) {
        double mu  = ls[0] / (double)M_CELLS;
        double var = ls2[0] / (double)M_CELLS - mu * mu;
        double rs  = 1.0 / sqrt(var + 1e-5);
        double gg  = (double)g[c];
        scale[c] = (float)(gg * rs);
        shift[c] = (float)((double)b[c] - mu * rs * gg);
    }
}

// ===================== conv5 (1x1) + bias, fused bn4+relu, channels-last input =====

__global__ __launch_bounds__(256) void k_conv5(const float* __restrict__ x4, // [M][48]
                                               const float* __restrict__ w,
                                               const float* __restrict__ bias,
                                               const float* __restrict__ scale,
                                               const float* __restrict__ shift,
                                               float* __restrict__ sem) {
    __shared__ float wl[N_CLS * 48];
    __shared__ float scl[48], shf[48], bl[N_CLS];
    int tid = threadIdx.x;
    for (int e = tid; e < N_CLS * 48; e += 256) wl[e] = w[e];
    if (tid < 48) { scl[tid] = scale[tid]; shf[tid] = shift[tid]; }
    if (tid < N_CLS) bl[tid] = bias[tid];
    __syncthreads();
    int p = blockIdx.x * 256 + tid;
    if (p >= M_CELLS) return;
    float inr[48];
    const float4* xp = (const float4*)(x4 + (size_t)p * 48);
    #pragma unroll
    for (int q = 0; q < 12; ++q) {
        float4 v = xp[q];
        inr[4*q+0] = v.x; inr[4*q+1] = v.y; inr[4*q+2] = v.z; inr[4*q+3] = v.w;
    }
    #pragma unroll
    for (int c = 0; c < 48; ++c)
        inr[c] = fmaxf(fmaf(inr[c], scl[c], shf[c]), 0.f);
    #pragma unroll
    for (int o = 0; o < N_CLS; ++o) {
        float a = bl[o];
        #pragma unroll
        for (int c = 0; c < 48; ++c) a = fmaf(inr[c], wl[o * 48 + c], a);
        sem[(size_t)o * M_CELLS + p] = a;
    }
}

__global__ __launch_bounds__(256) void k_copyout(const float* __restrict__ observed,
                                                 const float* __restrict__ hmap,
                                                 float* __restrict__ out) {
    int m = blockIdx.x * 256 + threadIdx.x;
    if (m < M_CELLS) {
        out[(size_t)N_CLS * M_CELLS + m] = observed[m];
        out[(size_t)N_CLS * M_CELLS + M_CELLS + m] = hmap[m];
    }
}

// ===================== host launcher =====================

extern "C" void kernel_launch(void* const* d_in, const int* in_sizes, int n_in,
                              void* d_out, int out_size, void* d_ws, size_t ws_size,
                              hipStream_t stream) {
    (void)in_sizes; (void)n_in; (void)out_size; (void)ws_size;

    const float* features = (const float*)d_in[0];
    const int*   proj     = (const int*)d_in[1];
    const int*   mask     = (const int*)d_in[2];
    const float* heights  = (const float*)d_in[3];
    const float* w_ih  = (const float*)d_in[6];
    const float* w_hh  = (const float*)d_in[7];
    const float* b_ih  = (const float*)d_in[8];
    const float* b_hh  = (const float*)d_in[9];
    const float* c1_w  = (const float*)d_in[10];
    const float* bn1_g = (const float*)d_in[11];
    const float* bn1_b = (const float*)d_in[12];
    const float* c2_w  = (const float*)d_in[13];
    const float* bn2_g = (const float*)d_in[14];
    const float* bn2_b = (const float*)d_in[15];
    const float* c3_w  = (const float*)d_in[16];
    const float* bn3_g = (const float*)d_in[17];
    const float* bn3_b = (const float*)d_in[18];
    const float* c4_w  = (const float*)d_in[19];
    const float* bn4_g = (const float*)d_in[20];
    const float* bn4_b = (const float*)d_in[21];
    const float* c5_w  = (const float*)d_in[22];
    const float* c5_b  = (const float*)d_in[23];

    // ---- workspace layout (max ~133.4 MB) ----
    char* ws = (char*)d_ws;
    float* state   = (float*)(ws);                    // [0, 64.0M)   scan..cvt1
    short* in1_cl  = (short*)(ws + 64000000);         // 36.49M       cvt1..conv1
    short* x1_cl   = (short*)(ws + 100500000);        // 18.24M       conv1..conv2
    short* x2_cl   = (short*)(ws + 118800000);        //  9.12M       conv2..conv3
    short* x3_cl   = (short*)(ws + 64000000);         //  9.12M alias dead in1_cl
    float* x4      = (float*)(ws + 74000000);         // 12.0M  alias dead in1_cl
    short* wm1     = (short*)(ws + 128000000);        //  3.21M
    short* wm2     = (short*)(ws + 131300000);        //  0.15M
    short* wm3     = (short*)(ws + 131500000);        //  0.07M
    short* wm4     = (short*)(ws + 131600000);        //  0.07M
    float* hmap     = (float*)(ws + 132000000);
    float* new_hmap = hmap + M_CELLS;
    float* observed = new_hmap + M_CELLS;
    int*   winner   = (int*)(observed + M_CELLS);
    int*   updlist  = winner + M_CELLS;
    int*   count    = updlist + M_CELLS;
    float* sums     = (float*)(count + 64);           // 512
    float* sums2    = sums + 512;
    float* scales   = sums2 + 512;
    float* shifts   = scales + 512;

    hipMemsetAsync(state, 0, (size_t)M_CELLS * D_MEM * sizeof(float), stream);
    hipMemsetAsync(hmap, 0, M_CELLS * sizeof(float), stream);
    hipMemsetAsync(observed, 0, M_CELLS * sizeof(float), stream);
    hipMemsetAsync(sums, 0, 1024 * sizeof(float), stream);
    hipMemsetAsync(in1_cl, 0, (size_t)PP * 256 * 2, stream);
    hipMemsetAsync(x1_cl, 0, (size_t)PP * 128 * 2, stream);
    hipMemsetAsync(x2_cl, 0, (size_t)PP * 64 * 2, stream);

    // weight pre-transforms (independent of scan)
    k_wprep<<<(49*32*128 + 255)/256, 256, 0, stream>>>(c1_w, wm1, 128, 256, 128, 256, 7);
    k_wprep<<<(9*16*64  + 255)/256, 256, 0, stream>>>(c2_w, wm2,  64, 128,  64, 128, 3);
    k_wprep<<<(9*8*64   + 255)/256, 256, 0, stream>>>(c3_w, wm3,  48,  64,  64,  64, 3);
    k_wprep<<<(9*8*64   + 255)/256, 256, 0, stream>>>(c4_w, wm4,  48,  48,  64,  64, 3);

    const int PB = (P_PIX + 255) / 256;
    const int MB = (M_CELLS + 255) / 256;
    const int GB = (M_CELLS + GCELLS - 1) / GCELLS;

    for (int t = 0; t < T_FRAMES; ++t) {
        const int2*  proj_t = (const int2*)(proj + (size_t)t * P_PIX * 2);
        const int*   mask_t = mask + (size_t)t * P_PIX;
        const float* h_t    = heights + (size_t)t * P_PIX;
        const float* f_t    = features + (size_t)t * C_FEAT * P_PIX;
        k_frame_init<<<MB, 256, 0, stream>>>(new_hmap, hmap, winner, count);
        k_scatter_max<<<PB, 256, 0, stream>>>(proj_t, mask_t, h_t, new_hmap);
        k_winner<<<PB, 256, 0, stream>>>(proj_t, mask_t, h_t, new_hmap, winner);
        k_compact<<<MB, 256, 0, stream>>>(new_hmap, hmap, observed, updlist, count);
        k_gru<<<GB, 256, 0, stream>>>(f_t, w_ih, w_hh, b_ih, b_hh,
                                      updlist, count, winner, state);
    }

    // state -> bf16 channels-last padded
    k_cvt1<<<(M_CELLS*32 + 255)/256, 256, 0, stream>>>(state, in1_cl);

    const int INT33_256 = (3 * PW + 3) * 256;
    const int INT33_128 = (3 * PW + 3) * 128;
    const int INT33_64  = (3 * PW + 3) * 64;

    // conv1 7x7 256->128 (MFMA)
    k_cmfma<256, 7, false><<<dim3(16, 16, 2), 256, 0, stream>>>(
        in1_cl, wm1, 128, x1_cl, 128);
    hipMemsetAsync(x3_cl, 0, (size_t)PP * 64 * 2, stream);   // in1_cl dead now
    k_bnstats_cl<128><<<50, 256, 0, stream>>>(x1_cl + INT33_128, sums + 0, sums2 + 0);
    k_bnfinal<<<1, 256, 0, stream>>>(sums + 0, sums2 + 0, bn1_g, bn1_b, 128, 128,
                                     scales + 0, shifts + 0);
    k_bnapply_cl<128><<<(M_CELLS*16 + 255)/256, 256, 0, stream>>>(
        x1_cl + INT33_128, scales + 0, shifts + 0);

    // conv2 3x3 128->64
    k_cmfma<128, 3, false><<<dim3(16, 16, 1), 256, 0, stream>>>(
        x1_cl, wm2, 64, x2_cl, 64);
    k_bnstats_cl<64><<<50, 256, 0, stream>>>(x2_cl + INT33_64, sums + 128, sums2 + 128);
    k_bnfinal<<<1, 256, 0, stream>>>(sums + 128, sums2 + 128, bn2_g, bn2_b, 64, 64,
                                     scales + 128, shifts + 128);
    k_bnapply_cl<64><<<(M_CELLS*8 + 255)/256, 256, 0, stream>>>(
        x2_cl + INT33_64, scales + 128, shifts + 128);

    // conv3 3x3 64->48 (oc padded to 64)
    k_cmfma<64, 3, false><<<dim3(16, 16, 1), 256, 0, stream>>>(
        x2_cl, wm3, 64, x3_cl, 64);
    k_bnstats_cl<64><<<50, 256, 0, stream>>>(x3_cl + INT33_64, sums + 192, sums2 + 192);
    k_bnfinal<<<1, 256, 0, stream>>>(sums + 192, sums2 + 192, bn3_g, bn3_b, 48, 64,
                                     scales + 192, shifts + 192);
    k_bnapply_cl<64><<<(M_CELLS*8 + 255)/256, 256, 0, stream>>>(
        x3_cl + INT33_64, scales + 192, shifts + 192);

    // conv4 3x3 48->48 -> compact f32 [M][48]
    k_cmfma<64, 3, true><<<dim3(16, 16, 1), 256, 0, stream>>>(
        x3_cl, wm4, 64, x4, 48);
    k_bnstats_s<<<48, 256, 0, stream>>>(x4, 48, bn4_g, bn4_b, scales + 256, shifts + 256);

    // conv5 1x1 48->20 + bias (fused bn4+relu) -> sem
    k_conv5<<<MB, 256, 0, stream>>>(x4, c5_w, c5_b, scales + 256, shifts + 256,
                                    (float*)d_out);

    k_copyout<<<MB, 256, 0, stream>>>(observed, hmap, (float*)d_out);
}

// Round 4
// 1973.197 us; speedup vs baseline: 5.3066x; 2.7353x over previous
//
#include <hip/hip_runtime.h>
#include <math.h>

// ---------------- problem dims (fixed by setup_inputs) ----------------
#define T_FRAMES 10
#define C_FEAT   64
#define IMG_H    480
#define IMG_W    640
#define P_PIX    (IMG_H*IMG_W)     // 307200
#define MAP_H    250
#define MAP_W    250
#define M_CELLS  (MAP_H*MAP_W)     // 62500
#define D_MEM    256
#define GATES    768
#define N_CLS    20
#define NPAD     62528             // M_CELLS padded to 64

// padded channels-last plane geometry: interior origin (3,3), rows 262, width 272
#define PW  272
#define PH  262
#define PP  (PH*PW)                // 71264 px per padded plane

typedef __attribute__((ext_vector_type(8))) short s16x8;   // 8 bf16 (4 VGPR)
typedef __attribute__((ext_vector_type(4))) float f32x4;   // MFMA acc

__device__ __forceinline__ unsigned short f2bf(float f) {
    unsigned int u = __float_as_uint(f);
    u += 0x7fffu + ((u >> 16) & 1u);      // RNE
    return (unsigned short)(u >> 16);
}
__device__ __forceinline__ float bf2f(unsigned short b) {
    return __uint_as_float(((unsigned int)b) << 16);
}

// ===================== scan-phase kernels =====================

__global__ __launch_bounds__(256) void k_frame_init(float* __restrict__ new_hmap,
                                                    const float* __restrict__ hmap,
                                                    int* __restrict__ winner,
                                                    int* __restrict__ count,
                                                    int* __restrict__ ps) {
    int i = blockIdx.x * 256 + threadIdx.x;
    if (i < M_CELLS) { new_hmap[i] = hmap[i]; winner[i] = -1; }
    if (i < P_PIX) ps[i] = -1;
    if (i == 0) *count = 0;
}

__global__ __launch_bounds__(256) void k_scatter_max(const int2* __restrict__ proj,
                                                     const int* __restrict__ mask,
                                                     const float* __restrict__ heights,
                                                     float* __restrict__ new_hmap) {
    int p = blockIdx.x * 256 + threadIdx.x;
    if (p >= P_PIX) return;
    if (mask[p]) return;                       // outlier -> -inf, never wins
    int2 pr = proj[p];
    int idx = MAP_W * pr.y + pr.x;
    float mh = heights[p] + 1000.0f;
    atomicMax((int*)(new_hmap + idx), __float_as_int(mh));  // all values >= 0
}

__global__ __launch_bounds__(256) void k_winner(const int2* __restrict__ proj,
                                                const int* __restrict__ mask,
                                                const float* __restrict__ heights,
                                                const float* __restrict__ new_hmap,
                                                int* __restrict__ winner) {
    int p = blockIdx.x * 256 + threadIdx.x;
    if (p >= P_PIX) return;
    if (mask[p]) return;
    int2 pr = proj[p];
    int idx = MAP_W * pr.y + pr.x;
    float mh = heights[p] + 1000.0f;
    if (mh == new_hmap[idx]) atomicMax(winner + idx, p);
}

__global__ __launch_bounds__(256) void k_compact(const float* __restrict__ new_hmap,
                                                 float* __restrict__ hmap,
                                                 float* __restrict__ observed,
                                                 int* __restrict__ updlist,
                                                 int* __restrict__ count,
                                                 const int* __restrict__ winner,
                                                 int* __restrict__ ps) {
    int m = blockIdx.x * 256 + threadIdx.x;
    if (m >= M_CELLS) return;
    float nh = new_hmap[m];
    if (nh > hmap[m]) {
        int pos = atomicAdd(count, 1);
        updlist[pos] = m;
        observed[m] = 1.0f;
        hmap[m] = nh;
        ps[winner[m]] = pos;       // inverse map: winner pixel -> compact slot
    }
}

// ===================== GRU activation gather =====================
// k_gx: pixel-order walk; winners write their 64-ch feature row (bf16) to Ag[slot][0..63].
// Coalesced per-channel reads -> each feature cacheline touched ~once.

__global__ __launch_bounds__(256) void k_gx(const float* __restrict__ feat,
                                            const int* __restrict__ ps,
                                            short* __restrict__ Ag) {
    int p = blockIdx.x * 256 + threadIdx.x;
    int i = ps[p];
    if (i < 0) return;
    short* dst = Ag + (size_t)i * 320;
    #pragma unroll
    for (int c8 = 0; c8 < 8; ++c8) {
        unsigned int pk[4];
        #pragma unroll
        for (int q = 0; q < 4; ++q) {
            float f0 = feat[(size_t)(c8 * 8 + 2 * q)     * P_PIX + p];
            float f1 = feat[(size_t)(c8 * 8 + 2 * q + 1) * P_PIX + p];
            pk[q] = (unsigned int)f2bf(f0) | ((unsigned int)f2bf(f1) << 16);
        }
        *(uint4*)(dst + c8 * 8) = make_uint4(pk[0], pk[1], pk[2], pk[3]);
    }
}

// k_gh: cell-order copy of old state rows (fp32 -> bf16) to Ag[slot][64..319].

__global__ __launch_bounds__(256) void k_gh(const float* __restrict__ state,
                                            const int* __restrict__ updlist,
                                            const int* __restrict__ count,
                                            short* __restrict__ Ag) {
    int n = *count;
    int idx = blockIdx.x * 256 + threadIdx.x;
    int i = idx >> 5, q = idx & 31;
    if (i >= n) return;
    int m = updlist[i];
    const float* sp = state + (size_t)m * D_MEM + q * 8;
    unsigned int pk[4];
    #pragma unroll
    for (int e = 0; e < 4; ++e)
        pk[e] = (unsigned int)f2bf(sp[2*e]) | ((unsigned int)f2bf(sp[2*e+1]) << 16);
    *(uint4*)(Ag + (size_t)i * 320 + 64 + q * 8) = make_uint4(pk[0], pk[1], pk[2], pk[3]);
}

// ===================== GRU weight prep: W'[1024][320] bf16, layout [k8][g'][8] =====
// rows 0..255 r (combined), 256..511 z (combined), 512..767 inn (x-only), 768..1023 hn (h-only)

__global__ __launch_bounds__(256) void k_wprep_gru(const float* __restrict__ w_ih,
                                                   const float* __restrict__ w_hh,
                                                   short* __restrict__ wq) {
    int idx = blockIdx.x * 256 + threadIdx.x;   // (k8, g'), 40*1024
    if (idx >= 40 * 1024) return;
    int gp = idx & 1023, k8 = idx >> 10;
    int tau = gp >> 8, gl = gp & 255;
    unsigned int pk[4];
    #pragma unroll
    for (int q = 0; q < 4; ++q) {
        unsigned int h2[2];
        #pragma unroll
        for (int e = 0; e < 2; ++e) {
            int k = k8 * 8 + q * 2 + e;
            float v = 0.f;
            if (tau == 0)      v = (k < 64) ? w_ih[(size_t)gl * 64 + k]
                                            : w_hh[(size_t)gl * 256 + (k - 64)];
            else if (tau == 1) v = (k < 64) ? w_ih[(size_t)(256 + gl) * 64 + k]
                                            : w_hh[(size_t)(256 + gl) * 256 + (k - 64)];
            else if (tau == 2) v = (k < 64) ? w_ih[(size_t)(512 + gl) * 64 + k] : 0.f;
            else               v = (k < 64) ? 0.f
                                            : w_hh[(size_t)(512 + gl) * 256 + (k - 64)];
            h2[e] = f2bf(v);
        }
        pk[q] = h2[0] | (h2[1] << 16);
    }
    *(uint4*)(wq + (size_t)idx * 8) = make_uint4(pk[0], pk[1], pk[2], pk[3]);
}

// ===================== MFMA GRU GEMM + fused epilogue =====================
// grid (4 gate-slices, ceil(n/64) cell-blocks); 256 thr = 4 waves x 16 cells.
// Per wave: 16 cells x 256 gates (4 each of r/z/inn/hn), K=320 in 10 chunks.
// No LDS: B-frags from compact Ag rows, A-frags from L2-resident wq.

__global__ __launch_bounds__(256) void k_grumm(const short* __restrict__ Ag,
                                               const short* __restrict__ wq,
                                               const float* __restrict__ b_ih,
                                               const float* __restrict__ b_hh,
                                               const int* __restrict__ updlist,
                                               const int* __restrict__ count,
                                               float* __restrict__ state) {
    int n = *count;
    int base = blockIdx.y * 64;
    if (base >= n) return;
    const int bz = blockIdx.x;
    const int tid = threadIdx.x;
    const int w = tid >> 6, l = tid & 63, u = l & 15, s = l >> 4;
    const int cell = base + 16 * w + u;

    f32x4 acc[16];
    #pragma unroll
    for (int f = 0; f < 16; ++f) acc[f] = (f32x4){0.f, 0.f, 0.f, 0.f};

    const short* brow = Ag + (size_t)cell * 320 + 8 * s;
    const short* wb   = wq + ((size_t)s * 1024 + bz * 64 + u) * 8;

    #pragma unroll 2
    for (int ck = 0; ck < 10; ++ck) {
        s16x8 b = *(const s16x8*)(brow + ck * 32);
        const short* wc = wb + (size_t)ck * 4 * 1024 * 8;
        #pragma unroll
        for (int f = 0; f < 16; ++f) {
            const int off = ((f >> 2) * 256 + (f & 3) * 16) * 8;
            s16x8 a = *(const s16x8*)(wc + off);
            acc[f] = __builtin_amdgcn_mfma_f32_16x16x32_bf16(a, b, acc[f], 0, 0, 0);
        }
    }

    if (cell >= n) return;
    const int m = updlist[cell];
    float* sp = state + (size_t)m * D_MEM;
    #pragma unroll
    for (int fq = 0; fq < 4; ++fq) {
        #pragma unroll
        for (int r = 0; r < 4; ++r) {
            int d  = bz * 64 + 16 * fq + 4 * s + r;
            float rr = acc[0  + fq][r] + b_ih[d]       + b_hh[d];
            float zz = acc[4  + fq][r] + b_ih[256 + d] + b_hh[256 + d];
            float ii = acc[8  + fq][r] + b_ih[512 + d];
            float hh = acc[12 + fq][r] + b_hh[512 + d];
            float rv = 1.f / (1.f + expf(-rr));
            float zv = 1.f / (1.f + expf(-zz));
            float nv = tanhf(ii + rv * hh);
            float h  = sp[d];
            sp[d] = (1.f - zv) * nv + zv * h;
        }
    }
}

// ===================== state -> padded channels-last bf16 =====================

__global__ __launch_bounds__(256) void k_cvt1(const float* __restrict__ state,
                                              short* __restrict__ in1) {
    int idx = blockIdx.x * 256 + threadIdx.x;       // (m, c8)
    if (idx >= M_CELLS * 32) return;
    int m = idx >> 5, c8 = (idx & 31) * 8;
    int y = m / MAP_W, x = m - y * MAP_W;
    const float* sp = state + (size_t)m * D_MEM + c8;
    unsigned int pk[4];
    #pragma unroll
    for (int q = 0; q < 4; ++q) {
        unsigned int lo = f2bf(sp[2*q]), hi = f2bf(sp[2*q+1]);
        pk[q] = lo | (hi << 16);
    }
    uint4 v = make_uint4(pk[0], pk[1], pk[2], pk[3]);
    *(uint4*)(in1 + ((size_t)(y + 3) * PW + (x + 3)) * 256 + c8) = v;
}

// ===================== conv weight pre-transform -> [tap][ci8][OCP][8] bf16 ========

__global__ __launch_bounds__(256) void k_wprep(const float* __restrict__ w,
                                               short* __restrict__ wm,
                                               int OC, int CIN, int OCP, int CINP, int KS) {
    int total = KS * KS * (CINP / 8) * OCP;
    int idx = blockIdx.x * 256 + threadIdx.x;
    if (idx >= total) return;
    int oc  = idx % OCP;
    int t2  = idx / OCP;
    int ci8 = t2 % (CINP / 8);
    int tap = t2 / (CINP / 8);
    unsigned int pk[4];
    #pragma unroll
    for (int q = 0; q < 4; ++q) {
        unsigned int h[2];
        #pragma unroll
        for (int e = 0; e < 2; ++e) {
            int ci = ci8 * 8 + 2*q + e;
            float v = (oc < OC && ci < CIN)
                ? w[((size_t)oc * CIN + ci) * KS * KS + tap] : 0.f;
            h[e] = f2bf(v);
        }
        pk[q] = h[0] | (h[1] << 16);
    }
    *(uint4*)(wm + (size_t)idx * 8) = make_uint4(pk[0], pk[1], pk[2], pk[3]);
}

// ===================== MFMA implicit-GEMM conv (validated R3) =====================

template<int CINP, int KS, bool F32OUT>
__global__ __launch_bounds__(256) void k_cmfma(const short* __restrict__ in,
                                               const short* __restrict__ wm,
                                               int OCT,
                                               void* __restrict__ out,
                                               int OCS) {
    constexpr int PAD = KS / 2;
    constexpr int PTW = 16 + KS - 1;
    __shared__ alignas(16) char patch[PTW * PTW * 64];

    const int tid = threadIdx.x;
    const int w   = tid >> 6;
    const int l   = tid & 63;
    const int u   = l & 15;
    const int s   = l >> 4;

    const int x0  = 3 + 16 * blockIdx.x;
    const int y0  = 3 + 16 * blockIdx.y;
    const int oc0 = 64 * blockIdx.z;

    f32x4 acc[4][4];   // [yy][o]
    #pragma unroll
    for (int yy = 0; yy < 4; ++yy)
        #pragma unroll
        for (int o = 0; o < 4; ++o)
            acc[yy][o] = (f32x4){0.f, 0.f, 0.f, 0.f};

    for (int ci0 = 0; ci0 < CINP; ci0 += 32) {
        __syncthreads();
        for (int e = tid; e < PTW * PTW * 4; e += 256) {
            int c8 = e & 3;
            int pp = e >> 2;
            int px = pp % PTW, py = pp / PTW;
            int gy = y0 - PAD + py, gx = x0 - PAD + px;
            const short* g = in + ((size_t)gy * PW + gx) * CINP + ci0 + c8 * 8;
            int lb = (((py * PTW + px) * 64) + c8 * 16) ^ ((px & 3) << 4);
            *(uint4*)(patch + lb) = *(const uint4*)g;
        }
        __syncthreads();

        const short* wb = wm + ((size_t)(ci0 / 8 + s) * OCT + oc0 + u) * 8;

        for (int ky = 0; ky < KS; ++ky) {
            for (int kx = 0; kx < KS; ++kx) {
                const int tap = ky * KS + kx;
                const short* wt = wb + (size_t)tap * (CINP / 8) * OCT * 8;
                s16x8 a[4];
                #pragma unroll
                for (int o = 0; o < 4; ++o)
                    a[o] = *(const s16x8*)(wt + o * 16 * 8);
                const int px = kx + u;
                const int lb0 = ((px * 64) + s * 16) ^ ((px & 3) << 4);
                #pragma unroll
                for (int yy = 0; yy < 4; ++yy) {
                    int py = 4 * w + yy + ky;
                    s16x8 b = *(const s16x8*)(patch + py * PTW * 64 + lb0);
                    #pragma unroll
                    for (int o = 0; o < 4; ++o)
                        acc[yy][o] = __builtin_amdgcn_mfma_f32_16x16x32_bf16(
                            a[o], b, acc[yy][o], 0, 0, 0);
                }
            }
        }
    }

    const int gx = x0 + u;
    if (gx >= 253) return;
    #pragma unroll
    for (int yy = 0; yy < 4; ++yy) {
        int gy = y0 + 4 * w + yy;
        if (gy >= 253) continue;
        #pragma unroll
        for (int o = 0; o < 4; ++o) {
            int oc = oc0 + o * 16 + s * 4;
            if constexpr (F32OUT) {
                int m = (gy - 3) * MAP_W + (gx - 3);
                float* op = (float*)out + (size_t)m * 48 + oc;
                #pragma unroll
                for (int r = 0; r < 4; ++r)
                    if (oc + r < 48) op[r] = acc[yy][o][r];
            } else {
                short* op = (short*)out + ((size_t)gy * PW + gx) * OCS + oc;
                unsigned int w0 = f2bf(acc[yy][o][0]) | ((unsigned int)f2bf(acc[yy][o][1]) << 16);
                unsigned int w1 = f2bf(acc[yy][o][2]) | ((unsigned int)f2bf(acc[yy][o][3]) << 16);
                *(uint2*)op = make_uint2(w0, w1);
            }
        }
    }
}

// ===================== BN stats / finalize / apply (channels-last) =====================

template<int CINP>
__global__ __launch_bounds__(256) void k_bnstats_cl(const short* __restrict__ in, // at (3,3)
                                                    float* __restrict__ sums,
                                                    float* __restrict__ sums2) {
    constexpr int QW = 256 / CINP;
    int c = threadIdx.x & (CINP - 1);
    int q = threadIdx.x / CINP;
    float s = 0.f, s2 = 0.f;
    int yb = blockIdx.x * 5;
    for (int y = yb; y < yb + 5; ++y)
        for (int x = q; x < MAP_W; x += QW) {
            float v = bf2f((unsigned short)in[((size_t)y * PW + x) * CINP + c]);
            s += v; s2 += v * v;
        }
    __shared__ float ls[256], ls2[256];
    ls[threadIdx.x] = s; ls2[threadIdx.x] = s2;
    __syncthreads();
    if (q == 0) {
        #pragma unroll
        for (int k = 1; k < QW; ++k) { s += ls[k * CINP + c]; s2 += ls2[k * CINP + c]; }
        atomicAdd(sums + c, s); atomicAdd(sums2 + c, s2);
    }
}

__global__ __launch_bounds__(256) void k_bnfinal(const float* __restrict__ sums,
                                                 const float* __restrict__ sums2,
                                                 const float* __restrict__ g,
                                                 const float* __restrict__ b,
                                                 int OC, int C,
                                                 float* __restrict__ scale,
                                                 float* __restrict__ shift) {
    int c = threadIdx.x;
    if (c >= C) return;
    if (c < OC) {
        float mu  = sums[c] * (1.f / M_CELLS);
        float var = sums2[c] * (1.f / M_CELLS) - mu * mu;
        float rs  = rsqrtf(var + 1e-5f);
        scale[c] = g[c] * rs;
        shift[c] = b[c] - mu * rs * g[c];
    } else { scale[c] = 0.f; shift[c] = 0.f; }
}

template<int CINP>
__global__ __launch_bounds__(256) void k_bnapply_cl(short* __restrict__ base, // at (3,3)
                                                    const float* __restrict__ scale,
                                                    const float* __restrict__ shift) {
    constexpr int NC8 = CINP / 8;
    int idx = blockIdx.x * 256 + threadIdx.x;
    if (idx >= M_CELLS * NC8) return;
    int p = idx / NC8, c8 = (idx % NC8) * 8;
    int y = p / MAP_W, x = p - y * MAP_W;
    short* ptr = base + ((size_t)y * PW + x) * CINP + c8;
    uint4 v = *(uint4*)ptr;
    unsigned int uu[4] = {v.x, v.y, v.z, v.w};
    unsigned int ro[4];
    #pragma unroll
    for (int q = 0; q < 4; ++q) {
        float f0 = bf2f((unsigned short)(uu[q] & 0xffffu));
        float f1 = bf2f((unsigned short)(uu[q] >> 16));
        f0 = fmaxf(fmaf(f0, scale[c8 + 2*q],     shift[c8 + 2*q]),     0.f);
        f1 = fmaxf(fmaf(f1, scale[c8 + 2*q + 1], shift[c8 + 2*q + 1]), 0.f);
        ro[q] = (unsigned int)f2bf(f0) | ((unsigned int)f2bf(f1) << 16);
    }
    *(uint4*)ptr = make_uint4(ro[0], ro[1], ro[2], ro[3]);
}

// BN stats for compact f32 channels-last [M][stride]
__global__ __launch_bounds__(256) void k_bnstats_s(const float* __restrict__ x,
                                                   int stride,
                                                   const float* __restrict__ g,
                                                   const float* __restrict__ b,
                                                   float* __restrict__ scale,
                                                   float* __restrict__ shift) {
    int c = blockIdx.x;
    const float* p = x + c;
    double s = 0.0, s2 = 0.0;
    for (int i = threadIdx.x; i < M_CELLS; i += 256) {
        float v = p[(size_t)i * stride];
        s += v; s2 += (double)v * v;
    }
    __shared__ double ls[256], ls2[256];
    int tid = threadIdx.x;
    ls[tid] = s; ls2[tid] = s2;
    __syncthreads();
    for (int off = 128; off > 0; off >>= 1) {
        if (tid < off) { ls[tid] += ls[tid + off]; ls2[tid] += ls2[tid + off]; }
        __syncthreads();
    }
    if (tid == 0) {
        double mu  = ls[0] / (double)M_CELLS;
        double var = ls2[0] / (double)M_CELLS - mu * mu;
        double rs  = 1.0 / sqrt(var + 1e-5);
        double gg  = (double)g[c];
        scale[c] = (float)(gg * rs);
        shift[c] = (float)((double)b[c] - mu * rs * gg);
    }
}

// ===================== conv5 (1x1) + bias, fused bn4+relu =====================

__global__ __launch_bounds__(256) void k_conv5(const float* __restrict__ x4, // [M][48]
                                               const float* __restrict__ w,
                                               const float* __restrict__ bias,
                                               const float* __restrict__ scale,
                                               const float* __restrict__ shift,
                                               float* __restrict__ sem) {
    __shared__ float wl[N_CLS * 48];
    __shared__ float scl[48], shf[48], bl[N_CLS];
    int tid = threadIdx.x;
    for (int e = tid; e < N_CLS * 48; e += 256) wl[e] = w[e];
    if (tid < 48) { scl[tid] = scale[tid]; shf[tid] = shift[tid]; }
    if (tid < N_CLS) bl[tid] = bias[tid];
    __syncthreads();
    int p = blockIdx.x * 256 + tid;
    if (p >= M_CELLS) return;
    float inr[48];
    const float4* xp = (const float4*)(x4 + (size_t)p * 48);
    #pragma unroll
    for (int q = 0; q < 12; ++q) {
        float4 v = xp[q];
        inr[4*q+0] = v.x; inr[4*q+1] = v.y; inr[4*q+2] = v.z; inr[4*q+3] = v.w;
    }
    #pragma unroll
    for (int c = 0; c < 48; ++c)
        inr[c] = fmaxf(fmaf(inr[c], scl[c], shf[c]), 0.f);
    #pragma unroll
    for (int o = 0; o < N_CLS; ++o) {
        float a = bl[o];
        #pragma unroll
        for (int c = 0; c < 48; ++c) a = fmaf(inr[c], wl[o * 48 + c], a);
        sem[(size_t)o * M_CELLS + p] = a;
    }
}

__global__ __launch_bounds__(256) void k_copyout(const float* __restrict__ observed,
                                                 const float* __restrict__ hmap,
                                                 float* __restrict__ out) {
    int m = blockIdx.x * 256 + threadIdx.x;
    if (m < M_CELLS) {
        out[(size_t)N_CLS * M_CELLS + m] = observed[m];
        out[(size_t)N_CLS * M_CELLS + M_CELLS + m] = hmap[m];
    }
}

// ===================== host launcher =====================

extern "C" void kernel_launch(void* const* d_in, const int* in_sizes, int n_in,
                              void* d_out, int out_size, void* d_ws, size_t ws_size,
                              hipStream_t stream) {
    (void)in_sizes; (void)n_in; (void)out_size; (void)ws_size;

    const float* features = (const float*)d_in[0];
    const int*   proj     = (const int*)d_in[1];
    const int*   mask     = (const int*)d_in[2];
    const float* heights  = (const float*)d_in[3];
    const float* w_ih  = (const float*)d_in[6];
    const float* w_hh  = (const float*)d_in[7];
    const float* b_ih  = (const float*)d_in[8];
    const float* b_hh  = (const float*)d_in[9];
    const float* c1_w  = (const float*)d_in[10];
    const float* bn1_g = (const float*)d_in[11];
    const float* bn1_b = (const float*)d_in[12];
    const float* c2_w  = (const float*)d_in[13];
    const float* bn2_g = (const float*)d_in[14];
    const float* bn2_b = (const float*)d_in[15];
    const float* c3_w  = (const float*)d_in[16];
    const float* bn3_g = (const float*)d_in[17];
    const float* bn3_b = (const float*)d_in[18];
    const float* c4_w  = (const float*)d_in[19];
    const float* bn4_g = (const float*)d_in[20];
    const float* bn4_b = (const float*)d_in[21];
    const float* c5_w  = (const float*)d_in[22];
    const float* c5_b  = (const float*)d_in[23];

    // ---- workspace layout (max ~137.1 MB), aliased by lifetime ----
    char* ws = (char*)d_ws;
    float* state   = (float*)(ws);                    // [0, 64.0M)       scan..cvt1
    short* Ag      = (short*)(ws + 64000000);         // 40.02M           scan only
    short* in1_cl  = (short*)(ws + 64000000);         // 36.49M  alias Ag, post-scan
    short* x3_cl   = (short*)(ws + 64000000);         //  9.12M  alias, post-conv1
    float* x4      = (float*)(ws + 74000000);         // 12.0M   alias, post-conv3
    int*   ps      = (int*)  (ws + 104100000);        //  1.23M  scan only (alias x1)
    short* x1_cl   = (short*)(ws + 104100000);        // 18.24M  conv1..conv2
    short* x2_cl   = (short*)(ws + 122400000);        //  9.12M  conv2..conv3
    short* wm1     = (short*)(ws + 131600000);        //  3.21M
    short* wm2     = (short*)(ws + 134820000);
    short* wm3     = (short*)(ws + 134970000);
    short* wm4     = (short*)(ws + 135050000);
    short* wq      = (short*)(ws + 135130000);        //  0.66M
    float* hmap     = (float*)(ws + 135800000);
    float* new_hmap = hmap + M_CELLS;
    float* observed = new_hmap + M_CELLS;
    int*   winner   = (int*)(observed + M_CELLS);
    int*   updlist  = winner + M_CELLS;
    int*   count    = updlist + M_CELLS;
    float* sums     = (float*)(count + 64);
    float* sums2    = sums + 512;
    float* scales   = sums2 + 512;
    float* shifts   = scales + 512;

    hipMemsetAsync(state, 0, (size_t)M_CELLS * D_MEM * sizeof(float), stream);
    hipMemsetAsync(hmap, 0, M_CELLS * sizeof(float), stream);
    hipMemsetAsync(observed, 0, M_CELLS * sizeof(float), stream);
    hipMemsetAsync(sums, 0, 1024 * sizeof(float), stream);
    hipMemsetAsync(x2_cl, 0, (size_t)PP * 64 * 2, stream);

    // weight pre-transforms (independent of scan)
    k_wprep_gru<<<160, 256, 0, stream>>>(w_ih, w_hh, wq);
    k_wprep<<<(49*32*128 + 255)/256, 256, 0, stream>>>(c1_w, wm1, 128, 256, 128, 256, 7);
    k_wprep<<<(9*16*64  + 255)/256, 256, 0, stream>>>(c2_w, wm2,  64, 128,  64, 128, 3);
    k_wprep<<<(9*8*64   + 255)/256, 256, 0, stream>>>(c3_w, wm3,  48,  64,  64,  64, 3);
    k_wprep<<<(9*8*64   + 255)/256, 256, 0, stream>>>(c4_w, wm4,  48,  48,  64,  64, 3);

    const int PB = (P_PIX + 255) / 256;              // 1200
    const int MB = (M_CELLS + 255) / 256;            // 245
    const int HB = (M_CELLS * 32 + 255) / 256;       // 7813
    const int CB = (NPAD / 64);                      // 977

    for (int t = 0; t < T_FRAMES; ++t) {
        const int2*  proj_t = (const int2*)(proj + (size_t)t * P_PIX * 2);
        const int*   mask_t = mask + (size_t)t * P_PIX;
        const float* h_t    = heights + (size_t)t * P_PIX;
        const float* f_t    = features + (size_t)t * C_FEAT * P_PIX;
        k_frame_init<<<PB, 256, 0, stream>>>(new_hmap, hmap, winner, count, ps);
        k_scatter_max<<<PB, 256, 0, stream>>>(proj_t, mask_t, h_t, new_hmap);
        k_winner<<<PB, 256, 0, stream>>>(proj_t, mask_t, h_t, new_hmap, winner);
        k_compact<<<MB, 256, 0, stream>>>(new_hmap, hmap, observed, updlist, count,
                                          winner, ps);
        k_gx<<<PB, 256, 0, stream>>>(f_t, ps, Ag);
        k_gh<<<HB, 256, 0, stream>>>(state, updlist, count, Ag);
        k_grumm<<<dim3(4, CB), 256, 0, stream>>>(Ag, wq, b_ih, b_hh,
                                                 updlist, count, state);
    }

    // Ag dead; zero its aliases' pads, then convert state -> bf16 channels-last
    hipMemsetAsync(in1_cl, 0, (size_t)PP * 256 * 2, stream);
    hipMemsetAsync(x1_cl, 0, (size_t)PP * 128 * 2, stream);
    k_cvt1<<<(M_CELLS*32 + 255)/256, 256, 0, stream>>>(state, in1_cl);

    const int INT33_128 = (3 * PW + 3) * 128;
    const int INT33_64  = (3 * PW + 3) * 64;

    // conv1 7x7 256->128 (MFMA)
    k_cmfma<256, 7, false><<<dim3(16, 16, 2), 256, 0, stream>>>(
        in1_cl, wm1, 128, x1_cl, 128);
    hipMemsetAsync(x3_cl, 0, (size_t)PP * 64 * 2, stream);   // in1_cl dead now
    k_bnstats_cl<128><<<50, 256, 0, stream>>>(x1_cl + INT33_128, sums + 0, sums2 + 0);
    k_bnfinal<<<1, 256, 0, stream>>>(sums + 0, sums2 + 0, bn1_g, bn1_b, 128, 128,
                                     scales + 0, shifts + 0);
    k_bnapply_cl<128><<<(M_CELLS*16 + 255)/256, 256, 0, stream>>>(
        x1_cl + INT33_128, scales + 0, shifts + 0);

    // conv2 3x3 128->64
    k_cmfma<128, 3, false><<<dim3(16, 16, 1), 256, 0, stream>>>(
        x1_cl, wm2, 64, x2_cl, 64);
    k_bnstats_cl<64><<<50, 256, 0, stream>>>(x2_cl + INT33_64, sums + 128, sums2 + 128);
    k_bnfinal<<<1, 256, 0, stream>>>(sums + 128, sums2 + 128, bn2_g, bn2_b, 64, 64,
                                     scales + 128, shifts + 128);
    k_bnapply_cl<64><<<(M_CELLS*8 + 255)/256, 256, 0, stream>>>(
        x2_cl + INT33_64, scales + 128, shifts + 128);

    // conv3 3x3 64->48 (oc padded to 64)
    k_cmfma<64, 3, false><<<dim3(16, 16, 1), 256, 0, stream>>>(
        x2_cl, wm3, 64, x3_cl, 64);
    k_bnstats_cl<64><<<50, 256, 0, stream>>>(x3_cl + INT33_64, sums + 192, sums2 + 192);
    k_bnfinal<<<1, 256, 0, stream>>>(sums + 192, sums2 + 192, bn3_g, bn3_b, 48, 64,
                                     scales + 192, shifts + 192);
    k_bnapply_cl<64><<<(M_CELLS*8 + 255)/256, 256, 0, stream>>>(
        x3_cl + INT33_64, scales + 192, shifts + 192);

    // conv4 3x3 48->48 -> compact f32 [M][48]
    k_cmfma<64, 3, true><<<dim3(16, 16, 1), 256, 0, stream>>>(
        x3_cl, wm4, 64, x4, 48);
    k_bnstats_s<<<48, 256, 0, stream>>>(x4, 48, bn4_g, bn4_b, scales + 256, shifts + 256);

    // conv5 1x1 48->20 + bias (fused bn4+relu) -> sem
    k_conv5<<<MB, 256, 0, stream>>>(x4, c5_w, c5_b, scales + 256, shifts + 256,
                                    (float*)d_out);

    k_copyout<<<MB, 256, 0, stream>>>(observed, hmap, (float*)d_out);
}